// Round 7
// baseline (13197.653 us; speedup 1.0000x reference)
//
#include <hip/hip_runtime.h>

#define TT   128
#define FF   64
#define HH   512
#define GG   2048    // 4H
#define K1   576
#define K2   1024
#define KB1  72      // K1/8
#define KB2  128     // K2/8
#define NBLK 256
#define QS   520     // Q row stride (halves): 1040B -> S/4 % 8 == 4 -> b128 conflict-free

using f16x8 = __attribute__((ext_vector_type(8))) _Float16;
using f16x4 = __attribute__((ext_vector_type(4))) _Float16;
using f32x4 = __attribute__((ext_vector_type(4))) float;

// ---------------------------------------------------------------------------
// Repack [U;W] (fp32 [K][2048]) -> MFMA-fragment-native fp16 (validated r1-r6):
// element (ct,kb,c,j) at ((ct*K8+kb)*16+c)*8+j holds B[k=kb*8+j][col], with
// col = (c&3)*512 + ct*4 + (c>>2)  (16-col tiles = 4 h-units x 4 gates).
// ---------------------------------------------------------------------------
__global__ void pack_weights(const float* __restrict__ U, const float* __restrict__ W,
                             const float* __restrict__ bias, int K, int Kh,
                             _Float16* __restrict__ Bp, float* __restrict__ pb)
{
    int K8 = K >> 3;
    int total = K * GG;
    for (int idx = blockIdx.x * blockDim.x + threadIdx.x; idx < total + GG;
         idx += gridDim.x * blockDim.x) {
        if (idx < total) {
            int j = idx & 7, c = (idx >> 3) & 15, rem = idx >> 7;
            int kb = rem % K8, ct = rem / K8;
            int k = kb * 8 + j;
            int col = (c & 3) * HH + ct * 4 + (c >> 2);
            float v = (k < Kh) ? U[k * GG + col] : W[(k - Kh) * GG + col];
            Bp[idx] = (_Float16)v;
        } else {
            int p = idx - total, ct = p >> 4, c = p & 15;
            pb[p] = bias[(c & 3) * HH + ct * 4 + (c >> 2)];
        }
    }
}

// DPP quad_perm broadcast (VALU; quad = the 4 gates of one unit). Validated r3-r6.
template <int CTRL>
__device__ __forceinline__ float qbcast(float v) {
    return __int_as_float(__builtin_amdgcn_mov_dpp(__float_as_int(v), CTRL, 0xF, 0xF, true));
}

// async global->LDS DMA, 16B/lane; LDS dest = uniform base + lane*16 (linear).
__device__ __forceinline__ void gld_lds16(const _Float16* g, _Float16* l) {
    __builtin_amdgcn_global_load_lds(
        (__attribute__((address_space(1))) const void*)g,
        (__attribute__((address_space(3))) void*)l, 16, 0, 0);
}

// counted-vmcnt barrier (T4): keep this chunk's staging in flight, drain older.
template <int N> __device__ __forceinline__ void s1_bar() {
    if constexpr (N == 1)       asm volatile("s_waitcnt vmcnt(1) lgkmcnt(0)\ns_barrier" ::: "memory");
    else if constexpr (N == 2)  asm volatile("s_waitcnt vmcnt(2) lgkmcnt(0)\ns_barrier" ::: "memory");
    else if constexpr (N == 8)  asm volatile("s_waitcnt vmcnt(8) lgkmcnt(0)\ns_barrier" ::: "memory");
    else if constexpr (N == 9)  asm volatile("s_waitcnt vmcnt(9) lgkmcnt(0)\ns_barrier" ::: "memory");
    else if constexpr (N == 10) asm volatile("s_waitcnt vmcnt(10) lgkmcnt(0)\ns_barrier" ::: "memory");
    else                        asm volatile("s_waitcnt vmcnt(0) lgkmcnt(0)\ns_barrier" ::: "memory");
    __builtin_amdgcn_sched_barrier(0);
}
__device__ __forceinline__ void s2_bar() {
    asm volatile("s_waitcnt lgkmcnt(0)\ns_barrier" ::: "memory");
    __builtin_amdgcn_sched_barrier(0);
}

// ---------------------------------------------------------------------------
// Gate epilogue (validated r4-r6). C/D 16x16: col=lane&15, row=kq*4+j. Quad
// lanes = {i,f,cin,o} of one unit. cs stride 33 (conflict-free), hst stride 40.
// ---------------------------------------------------------------------------
__device__ __forceinline__ void lstm_epi(
    f32x4 v4, float bias, float* __restrict__ cs, _Float16* __restrict__ hstp,
    int R0, int kq, int c, int ubase)
{
    const int gsel = c & 3;
    const int ub = ubase + (c >> 2);
#pragma unroll
    for (int j = 0; j < 4; ++j) {
        float v = v4[j] + bias;
        float vi = qbcast<0x00>(v);
        float vf = qbcast<0x55>(v);
        float vc = qbcast<0xAA>(v);
        float vo = qbcast<0xFF>(v);
        float ig = 1.f / (1.f + __expf(-vi));
        float fg = 1.f / (1.f + __expf(-vf));
        float og = 1.f / (1.f + __expf(-vo));
        float cin = vc > 0.f ? vc : 0.f;
        int Rl = kq * 4 + j;
        int R = R0 + Rl;
        float cp = cs[R * 33 + ub];
        float cn = fg * cp + ig * cin;
        float hn = og * (cn > 0.f ? cn : 0.f);
        if (gsel == 0) {
            cs[R * 33 + ub] = cn;
            hstp[Rl * 40 + ub] = (_Float16)hn;
        }
    }
}

#define MFMA16(av, bv, acc) \
    acc = __builtin_amdgcn_mfma_f32_16x16x32_f16(av, bv, acc, 0, 0, 0)

// ---------------------------------------------------------------------------
// Persistent 2-layer LSTM. 256 blocks (1/CU) x 256 threads (4 waves, 1/SIMD).
// Block (rg,cg): 128 rows x 128 gate-cols. Wave (g=w>>1, kh=w&1): col-group g
// (4 tiles = 64 cols), K-half kh. w1f (144 regs) in VGPR, w2f (256) in AGPR,
// pinned ONCE. 16-row chunks; Q 3-deep, DMA distance-2, counted-vmcnt raw
// barriers; Q row stride 1040B (bank-conflict-free b128, linear DMA).
// Rowgroup-local grid barrier (h rows never cross the 16-block rowgroup).
// ---------------------------------------------------------------------------
__global__ __launch_bounds__(256, 1) void lstm_persist(
    const float* __restrict__ x,
    const _Float16* __restrict__ Bp1, const float* __restrict__ pb1,
    const _Float16* __restrict__ Bp2, const float* __restrict__ pb2,
    const float* __restrict__ Wd, const float* __restrict__ bd,
    _Float16* __restrict__ h1b,   // [2][2048][512]
    _Float16* __restrict__ h2b,   // [2][2048][512]
    unsigned* __restrict__ bar,   // [16][32] rowgroup counters
    float* __restrict__ out)
{
    __shared__ _Float16 Q1[3][16 * QS];     // 48.75KB  h1 chunks
    __shared__ _Float16 Q2[3][16 * QS];     // 48.75KB  h2 chunks
    __shared__ _Float16 Xp[2][16][72];      // 4.5KB    x_t fp16
    __shared__ float    c1s[128 * 33];      // 16.5KB
    __shared__ float    c2s[128 * 33];      // 16.5KB
    __shared__ _Float16 hst[2][16][40];     // 2.5KB    [layer][row][unit]
    __shared__ float    xb[2][2][2][2][256];// 16KB     [layer][g][src_kh][j][lane*4]

    const int tid = threadIdx.x;
    const int w = tid >> 6, lane = tid & 63;
    const int g = w >> 1, kh = w & 1;
    const int b = blockIdx.x;
    const int rg = b >> 4, cg = b & 15;
    const int r0 = rg * 128;
    const int c = lane & 15, kq = lane >> 4;

    for (int i = tid; i < 128 * 33; i += 256) { c1s[i] = 0.f; c2s[i] = 0.f; }
    for (int i = tid; i < 2 * 16 * 40; i += 256) (&hst[0][0][0])[i] = (_Float16)0.f;

    // ---- one-time: weights -> registers; w1f VGPR (144), w2f AGPR (256) ----
    f16x8 w1f[4][9], w2f[4][16];
#pragma unroll
    for (int ti = 0; ti < 4; ++ti) {
        const int ct = cg * 8 + g * 4 + ti;
#pragma unroll
        for (int kc = 0; kc < 9; ++kc)
            w1f[ti][kc] = *(const f16x8*)(Bp1 +
                (((size_t)ct * KB1 + (kh * 9 + kc) * 4 + kq) * 16 + c) * 8);
#pragma unroll
        for (int kc = 0; kc < 16; ++kc)
            w2f[ti][kc] = *(const f16x8*)(Bp2 +
                (((size_t)ct * KB2 + (kh * 16 + kc) * 4 + kq) * 16 + c) * 8);
    }
#pragma unroll
    for (int ti = 0; ti < 4; ++ti) {
#pragma unroll
        for (int kc = 0; kc < 9; ++kc) asm volatile("" : "+v"(w1f[ti][kc]));
#pragma unroll
        for (int kc = 0; kc < 16; ++kc) asm volatile("" : "+a"(w2f[ti][kc]));
    }

    const int ct0 = cg * 8 + g * 4 + kh * 2;
    const float bias1v[2] = { pb1[(ct0 + 0) * 16 + c], pb1[(ct0 + 1) * 16 + c] };
    const float bias2v[2] = { pb2[(ct0 + 0) * 16 + c], pb2[(ct0 + 1) * 16 + c] };
    const int ub0 = (g * 4 + kh * 2) * 4;

    const int xrow = tid >> 4, xc4 = (tid & 15) * 4;

    for (int s = 0; s <= TT; ++s) {
        const int pr1 = (s + 1) & 1, pw1 = s & 1;
        const int pr2 = s & 1,       pw2 = (s + 1) & 1;
        const _Float16* h1r = h1b + (size_t)pr1 * 2048 * HH;
        const _Float16* h2r = h2b + (size_t)pr2 * 2048 * HH;
        _Float16* h1w = h1b + (size_t)pw1 * 2048 * HH;
        _Float16* h2w = h2b + (size_t)pw2 * 2048 * HH;
        const bool notLast = (s < TT);

        // ---- prologue: stage chunks 0,1 (DMA) + x chunk 0 ----
        {
#pragma unroll
            for (int i = 0; i < 4; ++i) {
                int r = w * 4 + i;
                gld_lds16(h1r + (size_t)(r0 + r) * HH + lane * 8, &Q1[0][r * QS]);
                gld_lds16(h2r + (size_t)(r0 + r) * HH + lane * 8, &Q2[0][r * QS]);
            }
            float4 xv{0.f, 0.f, 0.f, 0.f};
            if (notLast)
                xv = *(const float4*)(x + ((size_t)(r0 + xrow) * TT + s) * FF + xc4);
#pragma unroll
            for (int i = 0; i < 4; ++i) {
                int r = w * 4 + i;
                gld_lds16(h1r + (size_t)(r0 + 16 + r) * HH + lane * 8, &Q1[1][r * QS]);
                gld_lds16(h2r + (size_t)(r0 + 16 + r) * HH + lane * 8, &Q2[1][r * QS]);
            }
            if (notLast)
                *(f16x4*)&Xp[0][xrow][xc4] =
                    (f16x4){(_Float16)xv.x, (_Float16)xv.y, (_Float16)xv.z, (_Float16)xv.w};
        }
        s1_bar<8>();   // keep chunk-1's 8 DMA in flight; chunk-0 complete

#pragma unroll
        for (int ch = 0; ch < 8; ++ch) {
            const int buf = ch % 3;
            const int par = ch & 1;

            // ---- issue order matters for vmcnt counting: x first ----
            float4 xnext{0.f, 0.f, 0.f, 0.f};
            const bool havex = (ch < 7) && notLast;
            if (havex)
                xnext = *(const float4*)(x +
                    ((size_t)(r0 + (ch + 1) * 16 + xrow) * TT + s) * FF + xc4);

            // hst(ch-1) -> global, unconditional all-thread 8B (uniform vmcnt)
            if (ch >= 1) {
                int layer = tid >> 7, r = (tid >> 3) & 15, cq = tid & 7;
                f16x4 hv = *(const f16x4*)&hst[layer][r][cq * 4];
                _Float16* dst = (layer ? h2w : h1w)
                    + (size_t)(r0 + (ch - 1) * 16 + r) * HH + cg * 32 + cq * 4;
                *(f16x4*)dst = hv;
            }
            // DMA chunk ch+2 (distance-2)
            if (ch < 6) {
                const int gr = r0 + (ch + 2) * 16;
                _Float16* q1d = &Q1[(ch + 2) % 3][0];
                _Float16* q2d = &Q2[(ch + 2) % 3][0];
#pragma unroll
                for (int i = 0; i < 4; ++i) {
                    int r = w * 4 + i;
                    gld_lds16(h1r + (size_t)(gr + r) * HH + lane * 8, q1d + r * QS);
                    gld_lds16(h2r + (size_t)(gr + r) * HH + lane * 8, q2d + r * QS);
                }
            }

            const char* q1b = (const char*)&Q1[buf][0] + c * (QS * 2);
            const char* q2b = (const char*)&Q2[buf][0] + c * (QS * 2);

            // ---- L1 partial (K-half kh), 4 tiles ----
            f32x4 ownA0{0.f, 0.f, 0.f, 0.f}, ownA1 = ownA0;
            if (notLast) {
                f32x4 a0{0.f, 0.f, 0.f, 0.f}, a1 = a0, a2 = a0, a3 = a0;
                if (kh == 0) {
#pragma unroll
                    for (int kc = 0; kc < 9; ++kc) {
                        f16x8 av = *(const f16x8*)(q1b + kc * 64 + kq * 16);
                        MFMA16(av, w1f[0][kc], a0); MFMA16(av, w1f[1][kc], a1);
                        MFMA16(av, w1f[2][kc], a2); MFMA16(av, w1f[3][kc], a3);
                    }
                    *(f32x4*)&xb[0][g][0][0][lane * 4] = a2;
                    *(f32x4*)&xb[0][g][0][1][lane * 4] = a3;
                    ownA0 = a0; ownA1 = a1;
                } else {
#pragma unroll
                    for (int kc = 0; kc < 7; ++kc) {
                        f16x8 av = *(const f16x8*)(q1b + (kc + 9) * 64 + kq * 16);
                        MFMA16(av, w1f[0][kc], a0); MFMA16(av, w1f[1][kc], a1);
                        MFMA16(av, w1f[2][kc], a2); MFMA16(av, w1f[3][kc], a3);
                    }
                    {
                        f16x8 av = *(const f16x8*)&Xp[par][c][kq * 8];
                        MFMA16(av, w1f[0][7], a0); MFMA16(av, w1f[1][7], a1);
                        MFMA16(av, w1f[2][7], a2); MFMA16(av, w1f[3][7], a3);
                    }
                    {
                        f16x8 av = *(const f16x8*)&Xp[par][c][32 + kq * 8];
                        MFMA16(av, w1f[0][8], a0); MFMA16(av, w1f[1][8], a1);
                        MFMA16(av, w1f[2][8], a2); MFMA16(av, w1f[3][8], a3);
                    }
                    *(f32x4*)&xb[0][g][1][0][lane * 4] = a0;
                    *(f32x4*)&xb[0][g][1][1][lane * 4] = a1;
                    ownA0 = a2; ownA1 = a3;
                }
            }
            // ---- L2 partial (kh0: h2 via Q2; kh1: h1 via Q1) ----
            f32x4 ownB0{0.f, 0.f, 0.f, 0.f}, ownB1 = ownB0;
            if (s >= 1) {
                const char* qb = kh ? q1b : q2b;
                f32x4 b0{0.f, 0.f, 0.f, 0.f}, b1 = b0, b2 = b0, b3 = b0;
#pragma unroll
                for (int kc = 0; kc < 16; ++kc) {
                    f16x8 av = *(const f16x8*)(qb + kc * 64 + kq * 16);
                    MFMA16(av, w2f[0][kc], b0); MFMA16(av, w2f[1][kc], b1);
                    MFMA16(av, w2f[2][kc], b2); MFMA16(av, w2f[3][kc], b3);
                }
                if (kh == 0) {
                    *(f32x4*)&xb[1][g][0][0][lane * 4] = b2;
                    *(f32x4*)&xb[1][g][0][1][lane * 4] = b3;
                    ownB0 = b0; ownB1 = b1;
                } else {
                    *(f32x4*)&xb[1][g][1][0][lane * 4] = b0;
                    *(f32x4*)&xb[1][g][1][1][lane * 4] = b1;
                    ownB0 = b2; ownB1 = b3;
                }
            }

            // ---- S1: counted vmcnt (this chunk's ops stay in flight) ----
            if (notLast) {
                if (ch == 0) s1_bar<9>();
                else if (ch == 6) s1_bar<2>();
                else if (ch == 7) s1_bar<1>();
                else s1_bar<10>();
            } else {
                if (ch == 0) s1_bar<8>();
                else if (ch >= 6) s1_bar<1>();
                else s1_bar<9>();
            }

            // ---- combine + epilogue (own 2 tiles per layer) ----
            if (notLast) {
                ownA0 += *(const f32x4*)&xb[0][g][kh ^ 1][0][lane * 4];
                ownA1 += *(const f32x4*)&xb[0][g][kh ^ 1][1][lane * 4];
                lstm_epi(ownA0, bias1v[0], c1s, &hst[0][0][0], ch * 16, kq, c, ub0);
                lstm_epi(ownA1, bias1v[1], c1s, &hst[0][0][0], ch * 16, kq, c, ub0 + 4);
            }
            if (s >= 1) {
                ownB0 += *(const f32x4*)&xb[1][g][kh ^ 1][0][lane * 4];
                ownB1 += *(const f32x4*)&xb[1][g][kh ^ 1][1][lane * 4];
                lstm_epi(ownB0, bias2v[0], c2s, &hst[1][0][0], ch * 16, kq, c, ub0);
                lstm_epi(ownB1, bias2v[1], c2s, &hst[1][0][0], ch * 16, kq, c, ub0 + 4);
            }
            if (havex)
                *(f16x4*)&Xp[par ^ 1][xrow][xc4] =
                    (f16x4){(_Float16)xnext.x, (_Float16)xnext.y,
                            (_Float16)xnext.z, (_Float16)xnext.w};
            s2_bar();
        }

        // ---- tail: store hst(7); drain everything before rowgroup barrier ----
        {
            int layer = tid >> 7, r = (tid >> 3) & 15, cq = tid & 7;
            f16x4 hv = *(const f16x4*)&hst[layer][r][cq * 4];
            _Float16* dst = (layer ? h2w : h1w)
                + (size_t)(r0 + 112 + r) * HH + cg * 32 + cq * 4;
            *(f16x4*)dst = hv;
        }
        s1_bar<0>();   // vmcnt(0) lgkmcnt(0) + barrier

        // ---- rowgroup-local barrier (16 blocks share h rows) ----
        if (tid == 0) {
            __threadfence();
            __hip_atomic_fetch_add(&bar[rg * 32], 1u, __ATOMIC_ACQ_REL, __HIP_MEMORY_SCOPE_AGENT);
            const unsigned target = 16u * (unsigned)(s + 1);
            while (__hip_atomic_load(&bar[rg * 32], __ATOMIC_ACQUIRE, __HIP_MEMORY_SCOPE_AGENT) < target)
                __builtin_amdgcn_s_sleep(1);
            __threadfence();
        }
        __syncthreads();
    }

    // ---- dense head: out = h2_127 @ Wd + bd (cg==0 blocks; 2 threads/row) ----
    if (cg == 0) {
        const _Float16* hf = h2b + (size_t)((TT + 1) & 1) * 2048 * HH;
        int row = tid >> 1, part = tid & 1;
        const _Float16* hr = hf + (size_t)(r0 + row) * HH + part * 256;
        const float* wd = Wd + part * 256;
        float ssum = 0.f;
#pragma unroll
        for (int u8 = 0; u8 < 32; ++u8) {
            f16x8 hv = *(const f16x8*)(hr + u8 * 8);
#pragma unroll
            for (int k = 0; k < 8; ++k) ssum += (float)hv[k] * wd[u8 * 8 + k];
        }
        ssum += __shfl_xor(ssum, 1);
        if (part == 0) out[r0 + row] = ssum + bd[0];
    }
}

extern "C" void kernel_launch(void* const* d_in, const int* in_sizes, int n_in,
                              void* d_out, int out_size, void* d_ws, size_t ws_size,
                              hipStream_t stream)
{
    const float* x  = (const float*)d_in[0];
    const float* W1 = (const float*)d_in[1];
    const float* U1 = (const float*)d_in[2];
    const float* b1 = (const float*)d_in[3];
    const float* W2 = (const float*)d_in[4];
    const float* U2 = (const float*)d_in[5];
    const float* b2 = (const float*)d_in[6];
    const float* Wd = (const float*)d_in[7];
    const float* bd = (const float*)d_in[8];
    float* out = (float*)d_out;

    char* ws = (char*)d_ws;
    size_t off = 0;
    _Float16* Bp1 = (_Float16*)(ws + off); off += (size_t)K1 * GG * 2;
    _Float16* Bp2 = (_Float16*)(ws + off); off += (size_t)K2 * GG * 2;
    float*    pb1 = (float*)(ws + off);    off += (size_t)GG * 4;
    float*    pb2 = (float*)(ws + off);    off += (size_t)GG * 4;
    _Float16* h1b = (_Float16*)(ws + off); off += (size_t)2 * 2048 * HH * 2;
    _Float16* h2b = (_Float16*)(ws + off); off += (size_t)2 * 2048 * HH * 2;
    unsigned* bar = (unsigned*)(ws + off); off += 16 * 32 * 4;

    hipMemsetAsync(h1b, 0, (size_t)2 * 2048 * HH * 2, stream);
    hipMemsetAsync(h2b, 0, (size_t)2 * 2048 * HH * 2, stream);
    hipMemsetAsync(bar, 0, 16 * 32 * 4, stream);

    pack_weights<<<512, 256, 0, stream>>>(U1, W1, b1, K1, HH, Bp1, pb1);
    pack_weights<<<512, 256, 0, stream>>>(U2, W2, b2, K2, HH, Bp2, pb2);
    lstm_persist<<<NBLK, 256, 0, stream>>>(x, Bp1, pb1, Bp2, pb2, Wd, bd,
                                           h1b, h2b, bar, out);
}

// Round 8
// 10007.808 us; speedup vs baseline: 1.3187x; 1.3187x over previous
//
#include <hip/hip_runtime.h>

#define TT   128
#define FF   64
#define HH   512
#define GG   2048    // 4H
#define K1   576
#define K2   1024
#define KB1  72      // K1/8
#define KB2  128     // K2/8
#define NBLK 256
#define QS   520     // Q row stride in halves (1040B)

using f16x8 = __attribute__((ext_vector_type(8))) _Float16;
using f16x4 = __attribute__((ext_vector_type(4))) _Float16;
using f32x4 = __attribute__((ext_vector_type(4))) float;

// ---------------------------------------------------------------------------
// Repack [U;W] (fp32 [K][2048]) -> MFMA-fragment-native fp16 (validated r1-r7):
// element (ct,kb,c,j) at ((ct*K8+kb)*16+c)*8+j holds B[k=kb*8+j][col], with
// col = (c&3)*512 + ct*4 + (c>>2)  (16-col tiles = 4 h-units x 4 gates).
// ---------------------------------------------------------------------------
__global__ void pack_weights(const float* __restrict__ U, const float* __restrict__ W,
                             const float* __restrict__ bias, int K, int Kh,
                             _Float16* __restrict__ Bp, float* __restrict__ pb)
{
    int K8 = K >> 3;
    int total = K * GG;
    for (int idx = blockIdx.x * blockDim.x + threadIdx.x; idx < total + GG;
         idx += gridDim.x * blockDim.x) {
        if (idx < total) {
            int j = idx & 7, c = (idx >> 3) & 15, rem = idx >> 7;
            int kb = rem % K8, ct = rem / K8;
            int k = kb * 8 + j;
            int col = (c & 3) * HH + ct * 4 + (c >> 2);
            float v = (k < Kh) ? U[k * GG + col] : W[(k - Kh) * GG + col];
            Bp[idx] = (_Float16)v;
        } else {
            int p = idx - total, ct = p >> 4, c = p & 15;
            pb[p] = bias[(c & 3) * HH + ct * 4 + (c >> 2)];
        }
    }
}

// DPP quad_perm broadcast (VALU; quad = the 4 gates of one unit). Validated r3-r7.
template <int CTRL>
__device__ __forceinline__ float qbcast(float v) {
    return __int_as_float(__builtin_amdgcn_mov_dpp(__float_as_int(v), CTRL, 0xF, 0xF, true));
}

// async global->LDS DMA, 16B/lane; LDS dest = uniform base + lane*16 (linear).
__device__ __forceinline__ void gld_lds16(const _Float16* g, _Float16* l) {
    __builtin_amdgcn_global_load_lds(
        (__attribute__((address_space(1))) const void*)g,
        (__attribute__((address_space(3))) void*)l, 16, 0, 0);
}

// ---------------------------------------------------------------------------
// Gate epilogue (validated r4-r7). C/D 16x16: col=lane&15, row=kq*4+j. Quad
// lanes = {i,f,cin,o} of one unit. cs stride 33 (conflict-free), hst stride 40.
// ---------------------------------------------------------------------------
__device__ __forceinline__ void lstm_epi(
    f32x4 v4, float bias, float* __restrict__ cs, _Float16* __restrict__ hstp,
    int R0, int kq, int c, int ubase)
{
    const int gsel = c & 3;
    const int ub = ubase + (c >> 2);
#pragma unroll
    for (int j = 0; j < 4; ++j) {
        float v = v4[j] + bias;
        float vi = qbcast<0x00>(v);
        float vf = qbcast<0x55>(v);
        float vc = qbcast<0xAA>(v);
        float vo = qbcast<0xFF>(v);
        float ig = 1.f / (1.f + __expf(-vi));
        float fg = 1.f / (1.f + __expf(-vf));
        float og = 1.f / (1.f + __expf(-vo));
        float cin = vc > 0.f ? vc : 0.f;
        int Rl = kq * 4 + j;
        int R = R0 + Rl;
        float cp = cs[R * 33 + ub];
        float cn = fg * cp + ig * cin;
        float hn = og * (cn > 0.f ? cn : 0.f);
        if (gsel == 0) {
            cs[R * 33 + ub] = cn;
            hstp[Rl * 40 + ub] = (_Float16)hn;
        }
    }
}

#define MFMA16(av, bv, acc) \
    acc = __builtin_amdgcn_mfma_f32_16x16x32_f16(av, bv, acc, 0, 0, 0)

// ---------------------------------------------------------------------------
// Persistent 2-layer LSTM. 256 blocks (1/CU) x 256 threads (4 waves, 1/SIMD).
// XCD-LOCAL DECOMPOSITION (the r8 change): blocks with equal b%8 share an XCD
// (round-robin dispatch, 1 block/CU). rg = 2*(b&7) + ((b>>3)&1), cg = b>>4
// puts ALL 16 col-blocks of a rowgroup (and its h1b/h2b/x working set,
// ~1.5MB) on ONE XCD -> the per-superstep h-exchange (128KB/block) and the
// 16x-shared x slice are L2-hits instead of cross-die L3/HBM misses.
// Wave (g=w>>1, kh=w&1): col-group g (4 tiles = 64 cols), K-half kh. w1f (144
// regs) VGPR-pinned, w2f (256 regs) AGPR-pinned, once. 16-row chunks, 2-deep
// Q buffers, distance-1 DMA, plain __syncthreads (compiler schedules waits).
// Rowgroup barrier (16 blocks, now same-XCD).
// ---------------------------------------------------------------------------
__global__ __launch_bounds__(256, 1) void lstm_persist(
    const float* __restrict__ x,
    const _Float16* __restrict__ Bp1, const float* __restrict__ pb1,
    const _Float16* __restrict__ Bp2, const float* __restrict__ pb2,
    const float* __restrict__ Wd, const float* __restrict__ bd,
    _Float16* __restrict__ h1b,   // [2][2048][512]
    _Float16* __restrict__ h2b,   // [2][2048][512]
    unsigned* __restrict__ bar,   // [16][32] rowgroup counters
    float* __restrict__ out)
{
    __shared__ _Float16 Q1[2][16 * QS];     // 32.5KB h1 chunks
    __shared__ _Float16 Q2[2][16 * QS];     // 32.5KB h2 chunks
    __shared__ _Float16 Xp[2][16][72];      // 4.5KB  x_t fp16
    __shared__ float    c1s[128 * 33];      // 16.5KB
    __shared__ float    c2s[128 * 33];      // 16.5KB
    __shared__ _Float16 hst[2][16][40];     // 2.5KB  [layer][row][unit]
    __shared__ float    xb[2][2][2][2][256];// 16KB   [layer][g][src_kh][j][lane*4]

    const int tid = threadIdx.x;
    const int w = tid >> 6, lane = tid & 63;
    const int g = w >> 1, kh = w & 1;
    const int b = blockIdx.x;
    const int rg = 2 * (b & 7) + ((b >> 3) & 1);   // XCD-local rowgroup
    const int cg = b >> 4;                          // col-group
    const int r0 = rg * 128;
    const int c = lane & 15, kq = lane >> 4;

    for (int i = tid; i < 128 * 33; i += 256) { c1s[i] = 0.f; c2s[i] = 0.f; }
    for (int i = tid; i < 2 * 16 * 40; i += 256) (&hst[0][0][0])[i] = (_Float16)0.f;

    // ---- one-time: weights -> registers; w1f VGPR (144), w2f AGPR (256) ----
    f16x8 w1f[4][9], w2f[4][16];
#pragma unroll
    for (int ti = 0; ti < 4; ++ti) {
        const int ct = cg * 8 + g * 4 + ti;
#pragma unroll
        for (int kc = 0; kc < 9; ++kc)
            w1f[ti][kc] = *(const f16x8*)(Bp1 +
                (((size_t)ct * KB1 + (kh * 9 + kc) * 4 + kq) * 16 + c) * 8);
#pragma unroll
        for (int kc = 0; kc < 16; ++kc)
            w2f[ti][kc] = *(const f16x8*)(Bp2 +
                (((size_t)ct * KB2 + (kh * 16 + kc) * 4 + kq) * 16 + c) * 8);
    }
#pragma unroll
    for (int ti = 0; ti < 4; ++ti) {
#pragma unroll
        for (int kc = 0; kc < 9; ++kc) asm volatile("" : "+v"(w1f[ti][kc]));
#pragma unroll
        for (int kc = 0; kc < 16; ++kc) asm volatile("" : "+a"(w2f[ti][kc]));
    }

    const int ct0 = cg * 8 + g * 4 + kh * 2;
    const float bias1v[2] = { pb1[(ct0 + 0) * 16 + c], pb1[(ct0 + 1) * 16 + c] };
    const float bias2v[2] = { pb2[(ct0 + 0) * 16 + c], pb2[(ct0 + 1) * 16 + c] };
    const int ub0 = (g * 4 + kh * 2) * 4;

    const int xrow = tid >> 4, xc4 = (tid & 15) * 4;

    for (int s = 0; s <= TT; ++s) {
        const int pr1 = (s + 1) & 1, pw1 = s & 1;
        const int pr2 = s & 1,       pw2 = (s + 1) & 1;
        const _Float16* h1r = h1b + (size_t)pr1 * 2048 * HH;
        const _Float16* h2r = h2b + (size_t)pr2 * 2048 * HH;
        _Float16* h1w = h1b + (size_t)pw1 * 2048 * HH;
        _Float16* h2w = h2b + (size_t)pw2 * 2048 * HH;
        const bool notLast = (s < TT);

        // ---- prestage chunk 0 (DMA) + x chunk 0 ----
        {
#pragma unroll
            for (int i = 0; i < 4; ++i) {
                int r = w * 4 + i;
                gld_lds16(h1r + (size_t)(r0 + r) * HH + lane * 8, &Q1[0][r * QS]);
                gld_lds16(h2r + (size_t)(r0 + r) * HH + lane * 8, &Q2[0][r * QS]);
            }
            if (notLast) {
                float4 xv = *(const float4*)(x + ((size_t)(r0 + xrow) * TT + s) * FF + xc4);
                *(f16x4*)&Xp[0][xrow][xc4] =
                    (f16x4){(_Float16)xv.x, (_Float16)xv.y, (_Float16)xv.z, (_Float16)xv.w};
            }
        }
        __syncthreads();

#pragma unroll
        for (int ch = 0; ch < 8; ++ch) {
            const int buf = ch & 1;

            // ---- DMA prefetch chunk ch+1 (consumed next iter; drained at S1) ----
            if (ch < 7) {
                const int gr = r0 + (ch + 1) * 16;
#pragma unroll
                for (int i = 0; i < 4; ++i) {
                    int r = w * 4 + i;
                    gld_lds16(h1r + (size_t)(gr + r) * HH + lane * 8, &Q1[buf ^ 1][r * QS]);
                    gld_lds16(h2r + (size_t)(gr + r) * HH + lane * 8, &Q2[buf ^ 1][r * QS]);
                }
            }
            float4 xnext{0.f, 0.f, 0.f, 0.f};
            const bool havex = (ch < 7) && notLast;
            if (havex)
                xnext = *(const float4*)(x +
                    ((size_t)(r0 + (ch + 1) * 16 + xrow) * TT + s) * FF + xc4);

            // ---- hst(ch-1) -> global (L2-local now), unconditional 8B ----
            if (ch >= 1) {
                int layer = tid >> 7, r = (tid >> 3) & 15, cq = tid & 7;
                f16x4 hv = *(const f16x4*)&hst[layer][r][cq * 4];
                _Float16* dst = (layer ? h2w : h1w)
                    + (size_t)(r0 + (ch - 1) * 16 + r) * HH + cg * 32 + cq * 4;
                *(f16x4*)dst = hv;
            }

            const char* q1b = (const char*)&Q1[buf][0] + c * (QS * 2);
            const char* q2b = (const char*)&Q2[buf][0] + c * (QS * 2);

            // ---- L1 partial (K-half kh), 4 tiles ----
            f32x4 ownA0{0.f, 0.f, 0.f, 0.f}, ownA1 = ownA0;
            if (notLast) {
                f32x4 a0{0.f, 0.f, 0.f, 0.f}, a1 = a0, a2 = a0, a3 = a0;
                if (kh == 0) {
#pragma unroll
                    for (int kc = 0; kc < 9; ++kc) {
                        f16x8 av = *(const f16x8*)(q1b + kc * 64 + kq * 16);
                        MFMA16(av, w1f[0][kc], a0); MFMA16(av, w1f[1][kc], a1);
                        MFMA16(av, w1f[2][kc], a2); MFMA16(av, w1f[3][kc], a3);
                    }
                    *(f32x4*)&xb[0][g][0][0][lane * 4] = a2;
                    *(f32x4*)&xb[0][g][0][1][lane * 4] = a3;
                    ownA0 = a0; ownA1 = a1;
                } else {
#pragma unroll
                    for (int kc = 0; kc < 7; ++kc) {
                        f16x8 av = *(const f16x8*)(q1b + (kc + 9) * 64 + kq * 16);
                        MFMA16(av, w1f[0][kc], a0); MFMA16(av, w1f[1][kc], a1);
                        MFMA16(av, w1f[2][kc], a2); MFMA16(av, w1f[3][kc], a3);
                    }
                    {
                        f16x8 av = *(const f16x8*)&Xp[buf][c][kq * 8];
                        MFMA16(av, w1f[0][7], a0); MFMA16(av, w1f[1][7], a1);
                        MFMA16(av, w1f[2][7], a2); MFMA16(av, w1f[3][7], a3);
                    }
                    {
                        f16x8 av = *(const f16x8*)&Xp[buf][c][32 + kq * 8];
                        MFMA16(av, w1f[0][8], a0); MFMA16(av, w1f[1][8], a1);
                        MFMA16(av, w1f[2][8], a2); MFMA16(av, w1f[3][8], a3);
                    }
                    *(f32x4*)&xb[0][g][1][0][lane * 4] = a0;
                    *(f32x4*)&xb[0][g][1][1][lane * 4] = a1;
                    ownA0 = a2; ownA1 = a3;
                }
            }
            // ---- L2 partial (kh0: h2 via Q2; kh1: h1 via Q1) ----
            f32x4 ownB0{0.f, 0.f, 0.f, 0.f}, ownB1 = ownB0;
            if (s >= 1) {
                const char* qb = kh ? q1b : q2b;
                f32x4 b0{0.f, 0.f, 0.f, 0.f}, b1 = b0, b2 = b0, b3 = b0;
#pragma unroll
                for (int kc = 0; kc < 16; ++kc) {
                    f16x8 av = *(const f16x8*)(qb + kc * 64 + kq * 16);
                    MFMA16(av, w2f[0][kc], b0); MFMA16(av, w2f[1][kc], b1);
                    MFMA16(av, w2f[2][kc], b2); MFMA16(av, w2f[3][kc], b3);
                }
                if (kh == 0) {
                    *(f32x4*)&xb[1][g][0][0][lane * 4] = b2;
                    *(f32x4*)&xb[1][g][0][1][lane * 4] = b3;
                    ownB0 = b0; ownB1 = b1;
                } else {
                    *(f32x4*)&xb[1][g][1][0][lane * 4] = b0;
                    *(f32x4*)&xb[1][g][1][1][lane * 4] = b1;
                    ownB0 = b2; ownB1 = b3;
                }
            }
            __syncthreads();   // S1: partials + DMA(ch+1) complete

            // ---- combine + epilogue (own 2 tiles per layer) ----
            if (notLast) {
                ownA0 += *(const f32x4*)&xb[0][g][kh ^ 1][0][lane * 4];
                ownA1 += *(const f32x4*)&xb[0][g][kh ^ 1][1][lane * 4];
                lstm_epi(ownA0, bias1v[0], c1s, &hst[0][0][0], ch * 16, kq, c, ub0);
                lstm_epi(ownA1, bias1v[1], c1s, &hst[0][0][0], ch * 16, kq, c, ub0 + 4);
            }
            if (s >= 1) {
                ownB0 += *(const f32x4*)&xb[1][g][kh ^ 1][0][lane * 4];
                ownB1 += *(const f32x4*)&xb[1][g][kh ^ 1][1][lane * 4];
                lstm_epi(ownB0, bias2v[0], c2s, &hst[1][0][0], ch * 16, kq, c, ub0);
                lstm_epi(ownB1, bias2v[1], c2s, &hst[1][0][0], ch * 16, kq, c, ub0 + 4);
            }
            if (havex)
                *(f16x4*)&Xp[buf ^ 1][xrow][xc4] =
                    (f16x4){(_Float16)xnext.x, (_Float16)xnext.y,
                            (_Float16)xnext.z, (_Float16)xnext.w};
            __syncthreads();   // S2: epilogue LDS + Xp writes visible
        }

        // ---- tail: store hst(7); syncthreads drains vm+lgkm for all waves ----
        {
            int layer = tid >> 7, r = (tid >> 3) & 15, cq = tid & 7;
            f16x4 hv = *(const f16x4*)&hst[layer][r][cq * 4];
            _Float16* dst = (layer ? h2w : h1w)
                + (size_t)(r0 + 112 + r) * HH + cg * 32 + cq * 4;
            *(f16x4*)dst = hv;
        }
        __syncthreads();

        // ---- rowgroup barrier (16 blocks, same XCD -> L2-local spin) ----
        if (tid == 0) {
            __threadfence();
            __hip_atomic_fetch_add(&bar[rg * 32], 1u, __ATOMIC_ACQ_REL, __HIP_MEMORY_SCOPE_AGENT);
            const unsigned target = 16u * (unsigned)(s + 1);
            while (__hip_atomic_load(&bar[rg * 32], __ATOMIC_ACQUIRE, __HIP_MEMORY_SCOPE_AGENT) < target)
                __builtin_amdgcn_s_sleep(1);
            __threadfence();
        }
        __syncthreads();
    }

    // ---- dense head: out = h2_127 @ Wd + bd (cg==0 blocks; 2 threads/row) ----
    if (cg == 0) {
        const _Float16* hf = h2b + (size_t)((TT + 1) & 1) * 2048 * HH;
        int row = tid >> 1, part = tid & 1;
        const _Float16* hr = hf + (size_t)(r0 + row) * HH + part * 256;
        const float* wd = Wd + part * 256;
        float ssum = 0.f;
#pragma unroll
        for (int u8 = 0; u8 < 32; ++u8) {
            f16x8 hv = *(const f16x8*)(hr + u8 * 8);
#pragma unroll
            for (int k = 0; k < 8; ++k) ssum += (float)hv[k] * wd[u8 * 8 + k];
        }
        ssum += __shfl_xor(ssum, 1);
        if (part == 0) out[r0 + row] = ssum + bd[0];
    }
}

extern "C" void kernel_launch(void* const* d_in, const int* in_sizes, int n_in,
                              void* d_out, int out_size, void* d_ws, size_t ws_size,
                              hipStream_t stream)
{
    const float* x  = (const float*)d_in[0];
    const float* W1 = (const float*)d_in[1];
    const float* U1 = (const float*)d_in[2];
    const float* b1 = (const float*)d_in[3];
    const float* W2 = (const float*)d_in[4];
    const float* U2 = (const float*)d_in[5];
    const float* b2 = (const float*)d_in[6];
    const float* Wd = (const float*)d_in[7];
    const float* bd = (const float*)d_in[8];
    float* out = (float*)d_out;

    char* ws = (char*)d_ws;
    size_t off = 0;
    _Float16* Bp1 = (_Float16*)(ws + off); off += (size_t)K1 * GG * 2;
    _Float16* Bp2 = (_Float16*)(ws + off); off += (size_t)K2 * GG * 2;
    float*    pb1 = (float*)(ws + off);    off += (size_t)GG * 4;
    float*    pb2 = (float*)(ws + off);    off += (size_t)GG * 4;
    _Float16* h1b = (_Float16*)(ws + off); off += (size_t)2 * 2048 * HH * 2;
    _Float16* h2b = (_Float16*)(ws + off); off += (size_t)2 * 2048 * HH * 2;
    unsigned* bar = (unsigned*)(ws + off); off += 16 * 32 * 4;

    hipMemsetAsync(h1b, 0, (size_t)2 * 2048 * HH * 2, stream);
    hipMemsetAsync(h2b, 0, (size_t)2 * 2048 * HH * 2, stream);
    hipMemsetAsync(bar, 0, 16 * 32 * 4, stream);

    pack_weights<<<512, 256, 0, stream>>>(U1, W1, b1, K1, HH, Bp1, pb1);
    pack_weights<<<512, 256, 0, stream>>>(U2, W2, b2, K2, HH, Bp2, pb2);
    lstm_persist<<<NBLK, 256, 0, stream>>>(x, Bp1, pb1, Bp2, pb2, Wd, bd,
                                           h1b, h2b, bar, out);
}

// Round 9
// 6069.510 us; speedup vs baseline: 2.1744x; 1.6489x over previous
//
#include <hip/hip_runtime.h>

#define TT   128
#define FF   64
#define HH   512
#define GG   2048    // 4H
#define K1   576
#define K2   1024
#define KB1  72      // K1/8
#define KB2  128     // K2/8
#define NBLK 256
#define QS   520     // Q row stride in halves (1040B)

using f16x8 = __attribute__((ext_vector_type(8))) _Float16;
using f16x4 = __attribute__((ext_vector_type(4))) _Float16;
using f32x4 = __attribute__((ext_vector_type(4))) float;

// ---------------------------------------------------------------------------
// Coalesced repack (r9 rewrite): grid = K/8 blocks; block kb stages rows
// kb*8..kb*8+7 of [U;W] (fp32, coalesced float4 reads) into LDS fp16, then
// writes dest-linear 16B chunks. Dest layout (validated r1-r8): element
// (ct,kb,c,j) at ((ct*K8+kb)*16+c)*8+j holds B[k=kb*8+j][col],
// col = (c&3)*512 + ct*4 + (c>>2).
// ---------------------------------------------------------------------------
__global__ void pack_weights(const float* __restrict__ U, const float* __restrict__ W,
                             const float* __restrict__ bias, int K8, int Kh,
                             _Float16* __restrict__ Bp, float* __restrict__ pb)
{
    __shared__ _Float16 T[8][GG];   // 32 KB
    const int kb = blockIdx.x;
    const int tid = threadIdx.x;
    for (int i = tid; i < 8 * (GG / 4); i += 256) {
        int r = i / (GG / 4), c4 = (i % (GG / 4)) * 4;
        int k = kb * 8 + r;
        const float* src = (k < Kh) ? (U + (size_t)k * GG) : (W + (size_t)(k - Kh) * GG);
        float4 v = *(const float4*)(src + c4);
        T[r][c4 + 0] = (_Float16)v.x; T[r][c4 + 1] = (_Float16)v.y;
        T[r][c4 + 2] = (_Float16)v.z; T[r][c4 + 3] = (_Float16)v.w;
    }
    __syncthreads();
    for (int m = tid; m < 2048; m += 256) {
        int ct = m >> 4, c = m & 15;
        int col = (c & 3) * HH + ct * 4 + (c >> 2);
        f16x8 v;
#pragma unroll
        for (int j = 0; j < 8; ++j) v[j] = T[j][col];
        *(f16x8*)(Bp + (((size_t)ct * K8 + kb) * 16 + c) * 8) = v;
    }
    if (kb == 0)
        for (int p = tid; p < GG; p += 256) {
            int ct = p >> 4, c = p & 15;
            pb[p] = bias[(c & 3) * HH + ct * 4 + (c >> 2)];
        }
}

// DPP quad_perm broadcast (VALU; quad = the 4 gates of one unit). Validated r3-r8.
template <int CTRL>
__device__ __forceinline__ float qbcast(float v) {
    return __int_as_float(__builtin_amdgcn_mov_dpp(__float_as_int(v), CTRL, 0xF, 0xF, true));
}

// async global->LDS DMA, 16B/lane, aux=1 (sc0: bypass L1, read at L2).
// REQUIRED for h freshness now that no buffer_inv runs (r9): h lines never
// enter L1, every read is served by the XCD-shared L2.
__device__ __forceinline__ void gld_lds16_sc0(const _Float16* g, _Float16* l) {
    __builtin_amdgcn_global_load_lds(
        (__attribute__((address_space(1))) const void*)g,
        (__attribute__((address_space(3))) void*)l, 16, 0, 1);
}

// ---------------------------------------------------------------------------
// Gate epilogue (validated r4-r8). C/D 16x16: col=lane&15, row=kq*4+j. Quad
// lanes = {i,f,cin,o} of one unit. cs stride 33 (conflict-free), hst stride 40.
// ---------------------------------------------------------------------------
__device__ __forceinline__ void lstm_epi(
    f32x4 v4, float bias, float* __restrict__ cs, _Float16* __restrict__ hstp,
    int R0, int kq, int c, int ubase)
{
    const int gsel = c & 3;
    const int ub = ubase + (c >> 2);
#pragma unroll
    for (int j = 0; j < 4; ++j) {
        float v = v4[j] + bias;
        float vi = qbcast<0x00>(v);
        float vf = qbcast<0x55>(v);
        float vc = qbcast<0xAA>(v);
        float vo = qbcast<0xFF>(v);
        float ig = 1.f / (1.f + __expf(-vi));
        float fg = 1.f / (1.f + __expf(-vf));
        float og = 1.f / (1.f + __expf(-vo));
        float cin = vc > 0.f ? vc : 0.f;
        int Rl = kq * 4 + j;
        int R = R0 + Rl;
        float cp = cs[R * 33 + ub];
        float cn = fg * cp + ig * cin;
        float hn = og * (cn > 0.f ? cn : 0.f);
        if (gsel == 0) {
            cs[R * 33 + ub] = cn;
            hstp[Rl * 40 + ub] = (_Float16)hn;
        }
    }
}

#define MFMA16(av, bv, acc) \
    acc = __builtin_amdgcn_mfma_f32_16x16x32_f16(av, bv, acc, 0, 0, 0)

// ---------------------------------------------------------------------------
// Persistent 2-layer LSTM. 256 blocks (1/CU) x 256 threads (4 waves, 1/SIMD).
// XCD-local decomposition (validated r8: FETCH 3.96GB -> 76MB): rg =
// 2*(b&7)+((b>>3)&1), cg = b>>4 puts a rowgroup's 16 col-blocks + its h/x
// working set on ONE XCD -> h exchange is L2-local.
// r9 change: NO agent-scope fences. The rowgroup barrier uses RELAXED
// atomics (no buffer_inv/buffer_wbl2 per poll -> no L2 wb/inv storm); h DMA
// uses sc0 so reads are L2-coherent without L1 invalidation. Ordering: the
// __syncthreads before the increment drains all waves' stores to L2 (the
// XCD coherence point); the atomic carries device cpol so a wrong XCD-map
// degrades to slow-but-correct (absmax would flag stale h).
// ---------------------------------------------------------------------------
__global__ __launch_bounds__(256, 1) void lstm_persist(
    const float* __restrict__ x,
    const _Float16* __restrict__ Bp1, const float* __restrict__ pb1,
    const _Float16* __restrict__ Bp2, const float* __restrict__ pb2,
    const float* __restrict__ Wd, const float* __restrict__ bd,
    _Float16* __restrict__ h1b,   // [2][2048][512]
    _Float16* __restrict__ h2b,   // [2][2048][512]
    unsigned* __restrict__ bar,   // [16][32] rowgroup counters
    float* __restrict__ out)
{
    __shared__ _Float16 Q1[2][16 * QS];     // 32.5KB h1 chunks
    __shared__ _Float16 Q2[2][16 * QS];     // 32.5KB h2 chunks
    __shared__ _Float16 Xp[2][16][72];      // 4.5KB  x_t fp16
    __shared__ float    c1s[128 * 33];      // 16.5KB
    __shared__ float    c2s[128 * 33];      // 16.5KB
    __shared__ _Float16 hst[2][16][40];     // 2.5KB  [layer][row][unit]
    __shared__ float    xb[2][2][2][2][256];// 16KB   [layer][g][src_kh][j][lane*4]

    const int tid = threadIdx.x;
    const int w = tid >> 6, lane = tid & 63;
    const int g = w >> 1, kh = w & 1;
    const int b = blockIdx.x;
    const int rg = 2 * (b & 7) + ((b >> 3) & 1);   // XCD-local rowgroup
    const int cg = b >> 4;                          // col-group
    const int r0 = rg * 128;
    const int c = lane & 15, kq = lane >> 4;

    for (int i = tid; i < 128 * 33; i += 256) { c1s[i] = 0.f; c2s[i] = 0.f; }
    for (int i = tid; i < 2 * 16 * 40; i += 256) (&hst[0][0][0])[i] = (_Float16)0.f;

    // ---- one-time: weights -> registers; w1f VGPR (144), w2f AGPR (256) ----
    f16x8 w1f[4][9], w2f[4][16];
#pragma unroll
    for (int ti = 0; ti < 4; ++ti) {
        const int ct = cg * 8 + g * 4 + ti;
#pragma unroll
        for (int kc = 0; kc < 9; ++kc)
            w1f[ti][kc] = *(const f16x8*)(Bp1 +
                (((size_t)ct * KB1 + (kh * 9 + kc) * 4 + kq) * 16 + c) * 8);
#pragma unroll
        for (int kc = 0; kc < 16; ++kc)
            w2f[ti][kc] = *(const f16x8*)(Bp2 +
                (((size_t)ct * KB2 + (kh * 16 + kc) * 4 + kq) * 16 + c) * 8);
    }
#pragma unroll
    for (int ti = 0; ti < 4; ++ti) {
#pragma unroll
        for (int kc = 0; kc < 9; ++kc) asm volatile("" : "+v"(w1f[ti][kc]));
#pragma unroll
        for (int kc = 0; kc < 16; ++kc) asm volatile("" : "+a"(w2f[ti][kc]));
    }

    const int ct0 = cg * 8 + g * 4 + kh * 2;
    const float bias1v[2] = { pb1[(ct0 + 0) * 16 + c], pb1[(ct0 + 1) * 16 + c] };
    const float bias2v[2] = { pb2[(ct0 + 0) * 16 + c], pb2[(ct0 + 1) * 16 + c] };
    const int ub0 = (g * 4 + kh * 2) * 4;

    const int xrow = tid >> 4, xc4 = (tid & 15) * 4;

    for (int s = 0; s <= TT; ++s) {
        const int pr1 = (s + 1) & 1, pw1 = s & 1;
        const int pr2 = s & 1,       pw2 = (s + 1) & 1;
        const _Float16* h1r = h1b + (size_t)pr1 * 2048 * HH;
        const _Float16* h2r = h2b + (size_t)pr2 * 2048 * HH;
        _Float16* h1w = h1b + (size_t)pw1 * 2048 * HH;
        _Float16* h2w = h2b + (size_t)pw2 * 2048 * HH;
        const bool notLast = (s < TT);

        // ---- prestage chunk 0 (DMA sc0) + x chunk 0 ----
        {
#pragma unroll
            for (int i = 0; i < 4; ++i) {
                int r = w * 4 + i;
                gld_lds16_sc0(h1r + (size_t)(r0 + r) * HH + lane * 8, &Q1[0][r * QS]);
                gld_lds16_sc0(h2r + (size_t)(r0 + r) * HH + lane * 8, &Q2[0][r * QS]);
            }
            if (notLast) {
                float4 xv = *(const float4*)(x + ((size_t)(r0 + xrow) * TT + s) * FF + xc4);
                *(f16x4*)&Xp[0][xrow][xc4] =
                    (f16x4){(_Float16)xv.x, (_Float16)xv.y, (_Float16)xv.z, (_Float16)xv.w};
            }
        }
        __syncthreads();

#pragma unroll
        for (int ch = 0; ch < 8; ++ch) {
            const int buf = ch & 1;

            // ---- DMA prefetch chunk ch+1 (consumed next iter; drained at S1) ----
            if (ch < 7) {
                const int gr = r0 + (ch + 1) * 16;
#pragma unroll
                for (int i = 0; i < 4; ++i) {
                    int r = w * 4 + i;
                    gld_lds16_sc0(h1r + (size_t)(gr + r) * HH + lane * 8, &Q1[buf ^ 1][r * QS]);
                    gld_lds16_sc0(h2r + (size_t)(gr + r) * HH + lane * 8, &Q2[buf ^ 1][r * QS]);
                }
            }
            float4 xnext{0.f, 0.f, 0.f, 0.f};
            const bool havex = (ch < 7) && notLast;
            if (havex)
                xnext = *(const float4*)(x +
                    ((size_t)(r0 + (ch + 1) * 16 + xrow) * TT + s) * FF + xc4);

            // ---- hst(ch-1) -> global (L2-local), unconditional 8B ----
            if (ch >= 1) {
                int layer = tid >> 7, r = (tid >> 3) & 15, cq = tid & 7;
                f16x4 hv = *(const f16x4*)&hst[layer][r][cq * 4];
                _Float16* dst = (layer ? h2w : h1w)
                    + (size_t)(r0 + (ch - 1) * 16 + r) * HH + cg * 32 + cq * 4;
                *(f16x4*)dst = hv;
            }

            const char* q1b = (const char*)&Q1[buf][0] + c * (QS * 2);
            const char* q2b = (const char*)&Q2[buf][0] + c * (QS * 2);

            // ---- L1 partial (K-half kh), 4 tiles ----
            f32x4 ownA0{0.f, 0.f, 0.f, 0.f}, ownA1 = ownA0;
            if (notLast) {
                f32x4 a0{0.f, 0.f, 0.f, 0.f}, a1 = a0, a2 = a0, a3 = a0;
                if (kh == 0) {
#pragma unroll
                    for (int kc = 0; kc < 9; ++kc) {
                        f16x8 av = *(const f16x8*)(q1b + kc * 64 + kq * 16);
                        MFMA16(av, w1f[0][kc], a0); MFMA16(av, w1f[1][kc], a1);
                        MFMA16(av, w1f[2][kc], a2); MFMA16(av, w1f[3][kc], a3);
                    }
                    *(f32x4*)&xb[0][g][0][0][lane * 4] = a2;
                    *(f32x4*)&xb[0][g][0][1][lane * 4] = a3;
                    ownA0 = a0; ownA1 = a1;
                } else {
#pragma unroll
                    for (int kc = 0; kc < 7; ++kc) {
                        f16x8 av = *(const f16x8*)(q1b + (kc + 9) * 64 + kq * 16);
                        MFMA16(av, w1f[0][kc], a0); MFMA16(av, w1f[1][kc], a1);
                        MFMA16(av, w1f[2][kc], a2); MFMA16(av, w1f[3][kc], a3);
                    }
                    {
                        f16x8 av = *(const f16x8*)&Xp[buf][c][kq * 8];
                        MFMA16(av, w1f[0][7], a0); MFMA16(av, w1f[1][7], a1);
                        MFMA16(av, w1f[2][7], a2); MFMA16(av, w1f[3][7], a3);
                    }
                    {
                        f16x8 av = *(const f16x8*)&Xp[buf][c][32 + kq * 8];
                        MFMA16(av, w1f[0][8], a0); MFMA16(av, w1f[1][8], a1);
                        MFMA16(av, w1f[2][8], a2); MFMA16(av, w1f[3][8], a3);
                    }
                    *(f32x4*)&xb[0][g][1][0][lane * 4] = a0;
                    *(f32x4*)&xb[0][g][1][1][lane * 4] = a1;
                    ownA0 = a2; ownA1 = a3;
                }
            }
            // ---- L2 partial (kh0: h2 via Q2; kh1: h1 via Q1) ----
            f32x4 ownB0{0.f, 0.f, 0.f, 0.f}, ownB1 = ownB0;
            if (s >= 1) {
                const char* qb = kh ? q1b : q2b;
                f32x4 b0{0.f, 0.f, 0.f, 0.f}, b1 = b0, b2 = b0, b3 = b0;
#pragma unroll
                for (int kc = 0; kc < 16; ++kc) {
                    f16x8 av = *(const f16x8*)(qb + kc * 64 + kq * 16);
                    MFMA16(av, w2f[0][kc], b0); MFMA16(av, w2f[1][kc], b1);
                    MFMA16(av, w2f[2][kc], b2); MFMA16(av, w2f[3][kc], b3);
                }
                if (kh == 0) {
                    *(f32x4*)&xb[1][g][0][0][lane * 4] = b2;
                    *(f32x4*)&xb[1][g][0][1][lane * 4] = b3;
                    ownB0 = b0; ownB1 = b1;
                } else {
                    *(f32x4*)&xb[1][g][1][0][lane * 4] = b0;
                    *(f32x4*)&xb[1][g][1][1][lane * 4] = b1;
                    ownB0 = b2; ownB1 = b3;
                }
            }
            __syncthreads();   // S1: partials + DMA(ch+1) complete

            // ---- combine + epilogue (own 2 tiles per layer) ----
            if (notLast) {
                ownA0 += *(const f32x4*)&xb[0][g][kh ^ 1][0][lane * 4];
                ownA1 += *(const f32x4*)&xb[0][g][kh ^ 1][1][lane * 4];
                lstm_epi(ownA0, bias1v[0], c1s, &hst[0][0][0], ch * 16, kq, c, ub0);
                lstm_epi(ownA1, bias1v[1], c1s, &hst[0][0][0], ch * 16, kq, c, ub0 + 4);
            }
            if (s >= 1) {
                ownB0 += *(const f32x4*)&xb[1][g][kh ^ 1][0][lane * 4];
                ownB1 += *(const f32x4*)&xb[1][g][kh ^ 1][1][lane * 4];
                lstm_epi(ownB0, bias2v[0], c2s, &hst[1][0][0], ch * 16, kq, c, ub0);
                lstm_epi(ownB1, bias2v[1], c2s, &hst[1][0][0], ch * 16, kq, c, ub0 + 4);
            }
            if (havex)
                *(f16x4*)&Xp[buf ^ 1][xrow][xc4] =
                    (f16x4){(_Float16)xnext.x, (_Float16)xnext.y,
                            (_Float16)xnext.z, (_Float16)xnext.w};
            __syncthreads();   // S2: epilogue LDS + Xp writes visible
        }

        // ---- tail: store hst(7); syncthreads drains vm+lgkm for all waves ----
        {
            int layer = tid >> 7, r = (tid >> 3) & 15, cq = tid & 7;
            f16x4 hv = *(const f16x4*)&hst[layer][r][cq * 4];
            _Float16* dst = (layer ? h2w : h1w)
                + (size_t)(r0 + 112 + r) * HH + cg * 32 + cq * 4;
            *(f16x4*)dst = hv;
        }
        __syncthreads();   // all waves' stores drained to L2 before the signal

        // ---- rowgroup barrier, RELAXED (no wb/inv; L2 is the fence) ----
        if (tid == 0) {
            __hip_atomic_fetch_add(&bar[rg * 32], 1u,
                                   __ATOMIC_RELAXED, __HIP_MEMORY_SCOPE_AGENT);
            const unsigned target = 16u * (unsigned)(s + 1);
            while (__hip_atomic_load(&bar[rg * 32],
                                     __ATOMIC_RELAXED, __HIP_MEMORY_SCOPE_AGENT) < target)
                __builtin_amdgcn_s_sleep(2);
        }
        __syncthreads();
    }

    // ---- dense head: out = h2_127 @ Wd + bd (cg==0 blocks; 2 threads/row).
    // h2b lines never entered L1 (sc0 DMA) -> these plain loads miss to L2,
    // which holds the fresh final-parity h2. ----
    if (cg == 0) {
        const _Float16* hf = h2b + (size_t)((TT + 1) & 1) * 2048 * HH;
        int row = tid >> 1, part = tid & 1;
        const _Float16* hr = hf + (size_t)(r0 + row) * HH + part * 256;
        const float* wd = Wd + part * 256;
        float ssum = 0.f;
#pragma unroll
        for (int u8 = 0; u8 < 32; ++u8) {
            f16x8 hv = *(const f16x8*)(hr + u8 * 8);
#pragma unroll
            for (int k = 0; k < 8; ++k) ssum += (float)hv[k] * wd[u8 * 8 + k];
        }
        ssum += __shfl_xor(ssum, 1);
        if (part == 0) out[r0 + row] = ssum + bd[0];
    }
}

extern "C" void kernel_launch(void* const* d_in, const int* in_sizes, int n_in,
                              void* d_out, int out_size, void* d_ws, size_t ws_size,
                              hipStream_t stream)
{
    const float* x  = (const float*)d_in[0];
    const float* W1 = (const float*)d_in[1];
    const float* U1 = (const float*)d_in[2];
    const float* b1 = (const float*)d_in[3];
    const float* W2 = (const float*)d_in[4];
    const float* U2 = (const float*)d_in[5];
    const float* b2 = (const float*)d_in[6];
    const float* Wd = (const float*)d_in[7];
    const float* bd = (const float*)d_in[8];
    float* out = (float*)d_out;

    char* ws = (char*)d_ws;
    size_t off = 0;
    _Float16* Bp1 = (_Float16*)(ws + off); off += (size_t)K1 * GG * 2;
    _Float16* Bp2 = (_Float16*)(ws + off); off += (size_t)K2 * GG * 2;
    float*    pb1 = (float*)(ws + off);    off += (size_t)GG * 4;
    float*    pb2 = (float*)(ws + off);    off += (size_t)GG * 4;
    _Float16* h1b = (_Float16*)(ws + off); off += (size_t)2 * 2048 * HH * 2;
    _Float16* h2b = (_Float16*)(ws + off); off += (size_t)2 * 2048 * HH * 2;
    unsigned* bar = (unsigned*)(ws + off); off += 16 * 32 * 4;

    hipMemsetAsync(h1b, 0, (size_t)2 * 2048 * HH * 2, stream);
    hipMemsetAsync(h2b, 0, (size_t)2 * 2048 * HH * 2, stream);
    hipMemsetAsync(bar, 0, 16 * 32 * 4, stream);

    pack_weights<<<KB1, 256, 0, stream>>>(U1, W1, b1, KB1, HH, Bp1, pb1);
    pack_weights<<<KB2, 256, 0, stream>>>(U2, W2, b2, KB2, HH, Bp2, pb2);
    lstm_persist<<<NBLK, 256, 0, stream>>>(x, Bp1, pb1, Bp2, pb2, Wd, bd,
                                           h1b, h2b, bar, out);
}

// Round 10
// 4927.268 us; speedup vs baseline: 2.6785x; 1.2318x over previous
//
#include <hip/hip_runtime.h>

#define TT   128
#define FF   64
#define HH   512
#define GG   2048    // 4H
#define K1   576
#define K2   1024
#define KB1  72      // K1/8
#define KB2  128     // K2/8
#define NBLK 256
#define QS   520     // Q row stride in halves (1040B)

using f16x8 = __attribute__((ext_vector_type(8))) _Float16;
using f16x4 = __attribute__((ext_vector_type(4))) _Float16;
using f32x4 = __attribute__((ext_vector_type(4))) float;

// ---------------------------------------------------------------------------
// Coalesced repack (validated r9): block kb stages 8 rows of [U;W] into LDS,
// writes dest-linear 16B chunks. Layout: element (ct,kb,c,j) at
// ((ct*K8+kb)*16+c)*8+j holds B[k=kb*8+j][col], col=(c&3)*512+ct*4+(c>>2).
// ---------------------------------------------------------------------------
__global__ void pack_weights(const float* __restrict__ U, const float* __restrict__ W,
                             const float* __restrict__ bias, int K8, int Kh,
                             _Float16* __restrict__ Bp, float* __restrict__ pb)
{
    __shared__ _Float16 T[8][GG];
    const int kb = blockIdx.x;
    const int tid = threadIdx.x;
    for (int i = tid; i < 8 * (GG / 4); i += 256) {
        int r = i / (GG / 4), c4 = (i % (GG / 4)) * 4;
        int k = kb * 8 + r;
        const float* src = (k < Kh) ? (U + (size_t)k * GG) : (W + (size_t)(k - Kh) * GG);
        float4 v = *(const float4*)(src + c4);
        T[r][c4 + 0] = (_Float16)v.x; T[r][c4 + 1] = (_Float16)v.y;
        T[r][c4 + 2] = (_Float16)v.z; T[r][c4 + 3] = (_Float16)v.w;
    }
    __syncthreads();
    for (int m = tid; m < 2048; m += 256) {
        int ct = m >> 4, c = m & 15;
        int col = (c & 3) * HH + ct * 4 + (c >> 2);
        f16x8 v;
#pragma unroll
        for (int j = 0; j < 8; ++j) v[j] = T[j][col];
        *(f16x8*)(Bp + (((size_t)ct * K8 + kb) * 16 + c) * 8) = v;
    }
    if (kb == 0)
        for (int p = tid; p < GG; p += 256) {
            int ct = p >> 4, c = p & 15;
            pb[p] = bias[(c & 3) * HH + ct * 4 + (c >> 2)];
        }
}

// DPP quad_perm broadcast (VALU). Validated r3-r9.
template <int CTRL>
__device__ __forceinline__ float qbcast(float v) {
    return __int_as_float(__builtin_amdgcn_mov_dpp(__float_as_int(v), CTRL, 0xF, 0xF, true));
}

// async global->LDS DMA, 16B/lane, sc0 (L1-bypass; L2 is coherence point). r9.
__device__ __forceinline__ void gld_lds16_sc0(const _Float16* g, _Float16* l) {
    __builtin_amdgcn_global_load_lds(
        (__attribute__((address_space(1))) const void*)g,
        (__attribute__((address_space(3))) void*)l, 16, 0, 1);
}

// ---------------------------------------------------------------------------
// Gate epilogue, single-activation form (r10): each lane activates only its
// own gate (sigmoid for i,f,o; relu for cin), THEN broadcasts the activated
// value across the quad -> 2 trans ops per j instead of 6, ~1/3 the VALU.
// C/D 16x16: col=lane&15, row=kq*4+j. cs stride 33, hst stride 40. Same math.
// ---------------------------------------------------------------------------
__device__ __forceinline__ void lstm_epi(
    f32x4 v4, float bias, float* __restrict__ cs, _Float16* __restrict__ hstp,
    int R0, int kq, int c, int ubase)
{
    const int gsel = c & 3;
    const int ub = ubase + (c >> 2);
#pragma unroll
    for (int j = 0; j < 4; ++j) {
        float v = v4[j] + bias;
        float sig = 1.f / (1.f + __expf(-v));
        float act = (gsel == 2) ? (v > 0.f ? v : 0.f) : sig;
        float ig  = qbcast<0x00>(act);
        float fg  = qbcast<0x55>(act);
        float cin = qbcast<0xAA>(act);
        float og  = qbcast<0xFF>(act);
        int Rl = kq * 4 + j;
        int R = R0 + Rl;
        float cp = cs[R * 33 + ub];
        float cn = fg * cp + ig * cin;
        float hn = og * (cn > 0.f ? cn : 0.f);
        if (gsel == 0) {
            cs[R * 33 + ub] = cn;
            hstp[Rl * 40 + ub] = (_Float16)hn;
        }
    }
}

#define MFMA16(av, bv, acc) \
    acc = __builtin_amdgcn_mfma_f32_16x16x32_f16(av, bv, acc, 0, 0, 0)

// ---------------------------------------------------------------------------
// Persistent 2-layer LSTM. 256 blocks (1/CU) x 256 threads (4 waves, 1/SIMD).
// Geometry/residency as r6-r9 (validated): XCD-local rg=2*(b&7)+((b>>3)&1),
// cg=b>>4; wave (g=w>>1, kh=w&1) owns 4 tiles x half-K; w1f 144 VGPR,
// w2f 256 AGPR; relaxed rowgroup barrier; sc0 DMA.
// r10 change: SOFTWARE-PIPELINED chunk loop, ONE barrier per region:
//   region ch: DMA(ch+1) || hstore(ch-2) || combine+epi(ch-1) || partials(ch)
// Epilogue VALU/trans overlaps MFMA and DMA latency inside each region;
// xb and hst gain a parity dim; own-partials carried in regs across barrier.
// Barriers/superstep: 17 -> 11.
// ---------------------------------------------------------------------------
__global__ __launch_bounds__(256, 1) void lstm_persist(
    const float* __restrict__ x,
    const _Float16* __restrict__ Bp1, const float* __restrict__ pb1,
    const _Float16* __restrict__ Bp2, const float* __restrict__ pb2,
    const float* __restrict__ Wd, const float* __restrict__ bd,
    _Float16* __restrict__ h1b,   // [2][2048][512]
    _Float16* __restrict__ h2b,   // [2][2048][512]
    unsigned* __restrict__ bar,   // [16][32] rowgroup counters
    float* __restrict__ out)
{
    __shared__ _Float16 Q1[2][16 * QS];        // 32.5KB h1 chunks
    __shared__ _Float16 Q2[2][16 * QS];        // 32.5KB h2 chunks
    __shared__ _Float16 Xp[2][16][72];         // 4.5KB  x_t fp16
    __shared__ float    c1s[128 * 33];         // 16.5KB
    __shared__ float    c2s[128 * 33];         // 16.5KB
    __shared__ _Float16 hst[2][2][16][40];     // 5KB   [parity][layer][row][unit]
    __shared__ float    xb[2][2][2][2][2][256];// 32KB  [par][layer][g][skh][j][lane*4]

    const int tid = threadIdx.x;
    const int w = tid >> 6, lane = tid & 63;
    const int g = w >> 1, kh = w & 1;
    const int b = blockIdx.x;
    const int rg = 2 * (b & 7) + ((b >> 3) & 1);   // XCD-local rowgroup
    const int cg = b >> 4;
    const int r0 = rg * 128;
    const int c = lane & 15, kq = lane >> 4;

    for (int i = tid; i < 128 * 33; i += 256) { c1s[i] = 0.f; c2s[i] = 0.f; }

    // ---- one-time: weights -> registers; w1f VGPR (144), w2f AGPR (256) ----
    f16x8 w1f[4][9], w2f[4][16];
#pragma unroll
    for (int ti = 0; ti < 4; ++ti) {
        const int ct = cg * 8 + g * 4 + ti;
#pragma unroll
        for (int kc = 0; kc < 9; ++kc)
            w1f[ti][kc] = *(const f16x8*)(Bp1 +
                (((size_t)ct * KB1 + (kh * 9 + kc) * 4 + kq) * 16 + c) * 8);
#pragma unroll
        for (int kc = 0; kc < 16; ++kc)
            w2f[ti][kc] = *(const f16x8*)(Bp2 +
                (((size_t)ct * KB2 + (kh * 16 + kc) * 4 + kq) * 16 + c) * 8);
    }
#pragma unroll
    for (int ti = 0; ti < 4; ++ti) {
#pragma unroll
        for (int kc = 0; kc < 9; ++kc) asm volatile("" : "+v"(w1f[ti][kc]));
#pragma unroll
        for (int kc = 0; kc < 16; ++kc) asm volatile("" : "+a"(w2f[ti][kc]));
    }

    const int ct0 = cg * 8 + g * 4 + kh * 2;
    const float bias1v[2] = { pb1[(ct0 + 0) * 16 + c], pb1[(ct0 + 1) * 16 + c] };
    const float bias2v[2] = { pb2[(ct0 + 0) * 16 + c], pb2[(ct0 + 1) * 16 + c] };
    const int ub0 = (g * 4 + kh * 2) * 4;

    const int xrow = tid >> 4, xc4 = (tid & 15) * 4;

    for (int s = 0; s <= TT; ++s) {
        const int pr1 = (s + 1) & 1, pw1 = s & 1;
        const int pr2 = s & 1,       pw2 = (s + 1) & 1;
        const _Float16* h1r = h1b + (size_t)pr1 * 2048 * HH;
        const _Float16* h2r = h2b + (size_t)pr2 * 2048 * HH;
        _Float16* h1w = h1b + (size_t)pw1 * 2048 * HH;
        _Float16* h2w = h2b + (size_t)pw2 * 2048 * HH;
        const bool notLast = (s < TT);

        // ---- prologue: stage chunk 0 (DMA sc0) + x(0) ----
        {
#pragma unroll
            for (int i = 0; i < 4; ++i) {
                int r = w * 4 + i;
                gld_lds16_sc0(h1r + (size_t)(r0 + r) * HH + lane * 8, &Q1[0][r * QS]);
                gld_lds16_sc0(h2r + (size_t)(r0 + r) * HH + lane * 8, &Q2[0][r * QS]);
            }
            if (notLast) {
                float4 xv = *(const float4*)(x + ((size_t)(r0 + xrow) * TT + s) * FF + xc4);
                *(f16x4*)&Xp[0][xrow][xc4] =
                    (f16x4){(_Float16)xv.x, (_Float16)xv.y, (_Float16)xv.z, (_Float16)xv.w};
            }
        }
        __syncthreads();

        // own-partials carried across one barrier (regs)
        f32x4 ownA0{0.f, 0.f, 0.f, 0.f}, ownA1 = ownA0, ownB0 = ownA0, ownB1 = ownA0;

        // ---- pipelined regions: chunks 0..7, regions 0..9, 1 barrier each ----
        for (int ch = 0; ch <= 9; ++ch) {
            const int par = ch & 1;

            // (1) DMA prefetch chunk ch+1 -> Q[par^1]; x(ch+1) global load
            if (ch <= 6) {
                const int gr = r0 + (ch + 1) * 16;
#pragma unroll
                for (int i = 0; i < 4; ++i) {
                    int r = w * 4 + i;
                    gld_lds16_sc0(h1r + (size_t)(gr + r) * HH + lane * 8, &Q1[par ^ 1][r * QS]);
                    gld_lds16_sc0(h2r + (size_t)(gr + r) * HH + lane * 8, &Q2[par ^ 1][r * QS]);
                }
            }
            float4 xnext{0.f, 0.f, 0.f, 0.f};
            const bool havex = (ch <= 6) && notLast;
            if (havex)
                xnext = *(const float4*)(x +
                    ((size_t)(r0 + (ch + 1) * 16 + xrow) * TT + s) * FF + xc4);

            // (2) hst(ch-2) -> global (parity ch&1)
            if (ch >= 2) {
                int layer = tid >> 7, r = (tid >> 3) & 15, cq = tid & 7;
                bool go2 = layer ? (s >= 1) : notLast;
                if (go2) {
                    f16x4 hv = *(const f16x4*)&hst[par][layer][r][cq * 4];
                    _Float16* dst = (layer ? h2w : h1w)
                        + (size_t)(r0 + (ch - 2) * 16 + r) * HH + cg * 32 + cq * 4;
                    *(f16x4*)dst = hv;
                }
            }

            // (3) combine + epilogue for chunk ch-1 (xb parity par^1)
            if (ch >= 1 && ch <= 8) {
                const int R0 = (ch - 1) * 16;
                if (notLast) {
                    f32x4 f0 = ownA0 + *(const f32x4*)&xb[par ^ 1][0][g][kh ^ 1][0][lane * 4];
                    f32x4 f1 = ownA1 + *(const f32x4*)&xb[par ^ 1][0][g][kh ^ 1][1][lane * 4];
                    lstm_epi(f0, bias1v[0], c1s, &hst[par ^ 1][0][0][0], R0, kq, c, ub0);
                    lstm_epi(f1, bias1v[1], c1s, &hst[par ^ 1][0][0][0], R0, kq, c, ub0 + 4);
                }
                if (s >= 1) {
                    f32x4 f0 = ownB0 + *(const f32x4*)&xb[par ^ 1][1][g][kh ^ 1][0][lane * 4];
                    f32x4 f1 = ownB1 + *(const f32x4*)&xb[par ^ 1][1][g][kh ^ 1][1][lane * 4];
                    lstm_epi(f0, bias2v[0], c2s, &hst[par ^ 1][1][0][0], R0, kq, c, ub0);
                    lstm_epi(f1, bias2v[1], c2s, &hst[par ^ 1][1][0][0], R0, kq, c, ub0 + 4);
                }
            }

            // (4) MFMA partials for chunk ch (Q[par], Xp[par]); xb write parity par
            if (ch <= 7) {
                const char* q1b = (const char*)&Q1[par][0] + c * (QS * 2);
                const char* q2b = (const char*)&Q2[par][0] + c * (QS * 2);
                if (notLast) {
                    f32x4 a0{0.f, 0.f, 0.f, 0.f}, a1 = a0, a2 = a0, a3 = a0;
                    if (kh == 0) {
#pragma unroll
                        for (int kc = 0; kc < 9; ++kc) {
                            f16x8 av = *(const f16x8*)(q1b + kc * 64 + kq * 16);
                            MFMA16(av, w1f[0][kc], a0); MFMA16(av, w1f[1][kc], a1);
                            MFMA16(av, w1f[2][kc], a2); MFMA16(av, w1f[3][kc], a3);
                        }
                        *(f32x4*)&xb[par][0][g][0][0][lane * 4] = a2;
                        *(f32x4*)&xb[par][0][g][0][1][lane * 4] = a3;
                        ownA0 = a0; ownA1 = a1;
                    } else {
#pragma unroll
                        for (int kc = 0; kc < 7; ++kc) {
                            f16x8 av = *(const f16x8*)(q1b + (kc + 9) * 64 + kq * 16);
                            MFMA16(av, w1f[0][kc], a0); MFMA16(av, w1f[1][kc], a1);
                            MFMA16(av, w1f[2][kc], a2); MFMA16(av, w1f[3][kc], a3);
                        }
                        {
                            f16x8 av = *(const f16x8*)&Xp[par][c][kq * 8];
                            MFMA16(av, w1f[0][7], a0); MFMA16(av, w1f[1][7], a1);
                            MFMA16(av, w1f[2][7], a2); MFMA16(av, w1f[3][7], a3);
                        }
                        {
                            f16x8 av = *(const f16x8*)&Xp[par][c][32 + kq * 8];
                            MFMA16(av, w1f[0][8], a0); MFMA16(av, w1f[1][8], a1);
                            MFMA16(av, w1f[2][8], a2); MFMA16(av, w1f[3][8], a3);
                        }
                        *(f32x4*)&xb[par][0][g][1][0][lane * 4] = a0;
                        *(f32x4*)&xb[par][0][g][1][1][lane * 4] = a1;
                        ownA0 = a2; ownA1 = a3;
                    }
                }
                if (s >= 1) {
                    const char* qb = kh ? q1b : q2b;
                    f32x4 b0{0.f, 0.f, 0.f, 0.f}, b1 = b0, b2 = b0, b3 = b0;
#pragma unroll
                    for (int kc = 0; kc < 16; ++kc) {
                        f16x8 av = *(const f16x8*)(qb + kc * 64 + kq * 16);
                        MFMA16(av, w2f[0][kc], b0); MFMA16(av, w2f[1][kc], b1);
                        MFMA16(av, w2f[2][kc], b2); MFMA16(av, w2f[3][kc], b3);
                    }
                    if (kh == 0) {
                        *(f32x4*)&xb[par][1][g][0][0][lane * 4] = b2;
                        *(f32x4*)&xb[par][1][g][0][1][lane * 4] = b3;
                        ownB0 = b0; ownB1 = b1;
                    } else {
                        *(f32x4*)&xb[par][1][g][1][0][lane * 4] = b0;
                        *(f32x4*)&xb[par][1][g][1][1][lane * 4] = b1;
                        ownB0 = b2; ownB1 = b3;
                    }
                }
            }

            // (5) x(ch+1) -> Xp[par^1]
            if (havex)
                *(f16x4*)&Xp[par ^ 1][xrow][xc4] =
                    (f16x4){(_Float16)xnext.x, (_Float16)xnext.y,
                            (_Float16)xnext.z, (_Float16)xnext.w};

            __syncthreads();   // single barrier per region
        }

        // ---- rowgroup barrier, relaxed (validated r9) ----
        if (tid == 0) {
            __hip_atomic_fetch_add(&bar[rg * 32], 1u,
                                   __ATOMIC_RELAXED, __HIP_MEMORY_SCOPE_AGENT);
            const unsigned target = 16u * (unsigned)(s + 1);
            while (__hip_atomic_load(&bar[rg * 32],
                                     __ATOMIC_RELAXED, __HIP_MEMORY_SCOPE_AGENT) < target)
                __builtin_amdgcn_s_sleep(2);
        }
        __syncthreads();
    }

    // ---- dense head: out = h2_127 @ Wd + bd (cg==0 blocks; 2 threads/row) ----
    if (cg == 0) {
        const _Float16* hf = h2b + (size_t)((TT + 1) & 1) * 2048 * HH;
        int row = tid >> 1, part = tid & 1;
        const _Float16* hr = hf + (size_t)(r0 + row) * HH + part * 256;
        const float* wd = Wd + part * 256;
        float ssum = 0.f;
#pragma unroll
        for (int u8 = 0; u8 < 32; ++u8) {
            f16x8 hv = *(const f16x8*)(hr + u8 * 8);
#pragma unroll
            for (int k = 0; k < 8; ++k) ssum += (float)hv[k] * wd[u8 * 8 + k];
        }
        ssum += __shfl_xor(ssum, 1);
        if (part == 0) out[r0 + row] = ssum + bd[0];
    }
}

extern "C" void kernel_launch(void* const* d_in, const int* in_sizes, int n_in,
                              void* d_out, int out_size, void* d_ws, size_t ws_size,
                              hipStream_t stream)
{
    const float* x  = (const float*)d_in[0];
    const float* W1 = (const float*)d_in[1];
    const float* U1 = (const float*)d_in[2];
    const float* b1 = (const float*)d_in[3];
    const float* W2 = (const float*)d_in[4];
    const float* U2 = (const float*)d_in[5];
    const float* b2 = (const float*)d_in[6];
    const float* Wd = (const float*)d_in[7];
    const float* bd = (const float*)d_in[8];
    float* out = (float*)d_out;

    char* ws = (char*)d_ws;
    size_t off = 0;
    _Float16* Bp1 = (_Float16*)(ws + off); off += (size_t)K1 * GG * 2;
    _Float16* Bp2 = (_Float16*)(ws + off); off += (size_t)K2 * GG * 2;
    float*    pb1 = (float*)(ws + off);    off += (size_t)GG * 4;
    float*    pb2 = (float*)(ws + off);    off += (size_t)GG * 4;
    _Float16* h1b = (_Float16*)(ws + off); off += (size_t)2 * 2048 * HH * 2;
    _Float16* h2b = (_Float16*)(ws + off); off += (size_t)2 * 2048 * HH * 2;
    unsigned* bar = (unsigned*)(ws + off); off += 16 * 32 * 4;

    hipMemsetAsync(h1b, 0, (size_t)2 * 2048 * HH * 2, stream);
    hipMemsetAsync(h2b, 0, (size_t)2 * 2048 * HH * 2, stream);
    hipMemsetAsync(bar, 0, 16 * 32 * 4, stream);

    pack_weights<<<KB1, 256, 0, stream>>>(U1, W1, b1, KB1, HH, Bp1, pb1);
    pack_weights<<<KB2, 256, 0, stream>>>(U2, W2, b2, KB2, HH, Bp2, pb2);
    lstm_persist<<<NBLK, 256, 0, stream>>>(x, Bp1, pb1, Bp2, pb2, Wd, bd,
                                           h1b, h2b, bar, out);
}

// Round 11
// 4555.527 us; speedup vs baseline: 2.8971x; 1.0816x over previous
//
#include <hip/hip_runtime.h>

#define TT   128
#define FF   64
#define HH   512
#define GG   2048    // 4H
#define K1   576
#define K2   1024
#define KB1  72      // K1/8
#define KB2  128     // K2/8
#define NBLK 256
#define QS   520     // Q row stride in halves (1040B, 16B-aligned)

using f16x8 = __attribute__((ext_vector_type(8))) _Float16;
using f16x4 = __attribute__((ext_vector_type(4))) _Float16;
using f16x2 = __attribute__((ext_vector_type(2))) _Float16;
using f32x4 = __attribute__((ext_vector_type(4))) float;

// ---------------------------------------------------------------------------
// Coalesced repack (validated r9/r10): block kb stages 8 rows of [U;W] into
// LDS, writes dest-linear 16B chunks. Layout: element (ct,kb,c,j) at
// ((ct*K8+kb)*16+c)*8+j holds B[k=kb*8+j][col], col=(c&3)*512+ct*4+(c>>2).
// ---------------------------------------------------------------------------
__global__ void pack_weights(const float* __restrict__ U, const float* __restrict__ W,
                             const float* __restrict__ bias, int K8, int Kh,
                             _Float16* __restrict__ Bp, float* __restrict__ pb)
{
    __shared__ _Float16 T[8][GG];
    const int kb = blockIdx.x;
    const int tid = threadIdx.x;
    for (int i = tid; i < 8 * (GG / 4); i += 256) {
        int r = i / (GG / 4), c4 = (i % (GG / 4)) * 4;
        int k = kb * 8 + r;
        const float* src = (k < Kh) ? (U + (size_t)k * GG) : (W + (size_t)(k - Kh) * GG);
        float4 v = *(const float4*)(src + c4);
        T[r][c4 + 0] = (_Float16)v.x; T[r][c4 + 1] = (_Float16)v.y;
        T[r][c4 + 2] = (_Float16)v.z; T[r][c4 + 3] = (_Float16)v.w;
    }
    __syncthreads();
    for (int m = tid; m < 2048; m += 256) {
        int ct = m >> 4, c = m & 15;
        int col = (c & 3) * HH + ct * 4 + (c >> 2);
        f16x8 v;
#pragma unroll
        for (int j = 0; j < 8; ++j) v[j] = T[j][col];
        *(f16x8*)(Bp + (((size_t)ct * K8 + kb) * 16 + c) * 8) = v;
    }
    if (kb == 0)
        for (int p = tid; p < GG; p += 256) {
            int ct = p >> 4, c = p & 15;
            pb[p] = bias[(c & 3) * HH + ct * 4 + (c >> 2)];
        }
}

// DPP quad_perm broadcast (VALU). Validated r3-r10.
template <int CTRL>
__device__ __forceinline__ float qbcast(float v) {
    return __int_as_float(__builtin_amdgcn_mov_dpp(__float_as_int(v), CTRL, 0xF, 0xF, true));
}

// async global->LDS DMA, 16B/lane, sc0 (L1-bypass; L2 is coherence point). r9.
__device__ __forceinline__ void gld_lds16_sc0(const _Float16* g, _Float16* l) {
    __builtin_amdgcn_global_load_lds(
        (__attribute__((address_space(1))) const void*)g,
        (__attribute__((address_space(3))) void*)l, 16, 0, 1);
}

// ---------------------------------------------------------------------------
// Gate epilogue, single-activation form (validated r10): each lane activates
// its own gate, then quad-broadcasts the activated value (2 trans ops per j).
// C/D 16x16: col=lane&15, row=kq*4+j. cs stride 33, hst stride 40.
// ---------------------------------------------------------------------------
__device__ __forceinline__ void lstm_epi(
    f32x4 v4, float bias, float* __restrict__ cs, _Float16* __restrict__ hstp,
    int R0, int kq, int c, int ubase)
{
    const int gsel = c & 3;
    const int ub = ubase + (c >> 2);
#pragma unroll
    for (int j = 0; j < 4; ++j) {
        float v = v4[j] + bias;
        float sig = 1.f / (1.f + __expf(-v));
        float act = (gsel == 2) ? (v > 0.f ? v : 0.f) : sig;
        float ig  = qbcast<0x00>(act);
        float fg  = qbcast<0x55>(act);
        float cin = qbcast<0xAA>(act);
        float og  = qbcast<0xFF>(act);
        int Rl = kq * 4 + j;
        int R = R0 + Rl;
        float cp = cs[R * 33 + ub];
        float cn = fg * cp + ig * cin;
        float hn = og * (cn > 0.f ? cn : 0.f);
        if (gsel == 0) {
            cs[R * 33 + ub] = cn;
            hstp[Rl * 40 + ub] = (_Float16)hn;
        }
    }
}

#define MFMA16(av, bv, acc) \
    acc = __builtin_amdgcn_mfma_f32_16x16x32_f16(av, bv, acc, 0, 0, 0)

// ---------------------------------------------------------------------------
// Persistent 2-layer LSTM. 256 blocks (1/CU) x 512 threads (8 waves,
// 2 waves/SIMD -> TLP hides ds_read/MFMA/barrier latency; the r10 stall).
// r11 structure: wave w owns ONE 16-col tile ct=cg*8+w of BOTH layers,
// FULL K -> 50 f16x8 = 200 regs, all AGPR-pinned ("+a"); 256-reg budget at
// 2 waves/EU leaves ~56 VGPRs for the working set. Full-K kills the split-K
// xb exchange (no combine phase, -32KB LDS). Pipeline: 1 barrier per region:
//   region ch: DMA(ch+1) || hstore(ch-1) || MFMA(ch)+epi(ch) || x(ch+1)
// XCD-local rg=2*(b&7)+((b>>3)&1) (validated r8); relaxed rowgroup barrier
// (validated r9); sc0 DMA; acc split 2-way per layer for MFMA-chain ILP.
// ---------------------------------------------------------------------------
__global__ __launch_bounds__(512, 2) void lstm_persist(
    const float* __restrict__ x,
    const _Float16* __restrict__ Bp1, const float* __restrict__ pb1,
    const _Float16* __restrict__ Bp2, const float* __restrict__ pb2,
    const float* __restrict__ Wd, const float* __restrict__ bd,
    _Float16* __restrict__ h1b,   // [2][2048][512]
    _Float16* __restrict__ h2b,   // [2][2048][512]
    unsigned* __restrict__ bar,   // [16][32] rowgroup counters
    float* __restrict__ out)
{
    __shared__ _Float16 Q1[2][16 * QS];     // 32.5KB h1 chunks
    __shared__ _Float16 Q2[2][16 * QS];     // 32.5KB h2 chunks
    __shared__ _Float16 Xp[2][16][72];      // 4.5KB  x_t fp16
    __shared__ float    c1s[128 * 33];      // 16.5KB
    __shared__ float    c2s[128 * 33];      // 16.5KB
    __shared__ _Float16 hst[2][2][16][40];  // 5KB   [parity][layer][row][unit]

    const int tid = threadIdx.x;
    const int w = tid >> 6, lane = tid & 63;
    const int b = blockIdx.x;
    const int rg = 2 * (b & 7) + ((b >> 3) & 1);   // XCD-local rowgroup
    const int cg = b >> 4;
    const int r0 = rg * 128;
    const int c = lane & 15, kq = lane >> 4;

    for (int i = tid; i < 128 * 33; i += 512) { c1s[i] = 0.f; c2s[i] = 0.f; }
    for (int i = tid; i < 2 * 2 * 16 * 40; i += 512) (&hst[0][0][0][0])[i] = (_Float16)0.f;

    // ---- one-time: ALL weights -> AGPRs (200 regs/lane, "+a" pinned) ----
    const int ct = cg * 8 + w;
    f16x8 w1f[18], w2f[32];
#pragma unroll
    for (int kc = 0; kc < 18; ++kc)
        w1f[kc] = *(const f16x8*)(Bp1 + (((size_t)ct * KB1 + kc * 4 + kq) * 16 + c) * 8);
#pragma unroll
    for (int kc = 0; kc < 32; ++kc)
        w2f[kc] = *(const f16x8*)(Bp2 + (((size_t)ct * KB2 + kc * 4 + kq) * 16 + c) * 8);
#pragma unroll
    for (int kc = 0; kc < 18; ++kc) asm volatile("" : "+a"(w1f[kc]));
#pragma unroll
    for (int kc = 0; kc < 32; ++kc) asm volatile("" : "+a"(w2f[kc]));

    const float bias1 = pb1[ct * 16 + c];
    const float bias2 = pb2[ct * 16 + c];
    const int ub0 = w * 4;

    const int xrow = tid >> 5, xc2 = (tid & 31) * 2;

    for (int s = 0; s <= TT; ++s) {
        const int pr1 = (s + 1) & 1, pw1 = s & 1;
        const int pr2 = s & 1,       pw2 = (s + 1) & 1;
        const _Float16* h1r = h1b + (size_t)pr1 * 2048 * HH;
        const _Float16* h2r = h2b + (size_t)pr2 * 2048 * HH;
        _Float16* h1w = h1b + (size_t)pw1 * 2048 * HH;
        _Float16* h2w = h2b + (size_t)pw2 * 2048 * HH;
        const bool notLast = (s < TT);

        // ---- prologue: stage chunk 0 (DMA sc0) + x(0) ----
        {
#pragma unroll
            for (int i = 0; i < 2; ++i) {
                int r = w * 2 + i;
                gld_lds16_sc0(h1r + (size_t)(r0 + r) * HH + lane * 8, &Q1[0][r * QS]);
                gld_lds16_sc0(h2r + (size_t)(r0 + r) * HH + lane * 8, &Q2[0][r * QS]);
            }
            if (notLast) {
                float2 xv = *(const float2*)(x + ((size_t)(r0 + xrow) * TT + s) * FF + xc2);
                *(f16x2*)&Xp[0][xrow][xc2] = (f16x2){(_Float16)xv.x, (_Float16)xv.y};
            }
        }
        __syncthreads();

        // ---- pipelined regions: 1 barrier each ----
        for (int ch = 0; ch <= 8; ++ch) {
            const int par = ch & 1;

            // (1) DMA prefetch chunk ch+1 -> Q[par^1]
            if (ch <= 6) {
                const int gr = r0 + (ch + 1) * 16;
#pragma unroll
                for (int i = 0; i < 2; ++i) {
                    int r = w * 2 + i;
                    gld_lds16_sc0(h1r + (size_t)(gr + r) * HH + lane * 8, &Q1[par ^ 1][r * QS]);
                    gld_lds16_sc0(h2r + (size_t)(gr + r) * HH + lane * 8, &Q2[par ^ 1][r * QS]);
                }
            }
            float2 xnext{0.f, 0.f};
            const bool havex = (ch <= 6) && notLast;
            if (havex)
                xnext = *(const float2*)(x +
                    ((size_t)(r0 + (ch + 1) * 16 + xrow) * TT + s) * FF + xc2);

            // (2) hstore chunk ch-1 from hst[par^1] (256 threads, f16x4)
            if (ch >= 1 && tid < 256) {
                int layer = tid >> 7, r = (tid >> 3) & 15, cq = tid & 7;
                f16x4 hv = *(const f16x4*)&hst[par ^ 1][layer][r][cq * 4];
                _Float16* dst = (layer ? h2w : h1w)
                    + (size_t)(r0 + (ch - 1) * 16 + r) * HH + cg * 32 + cq * 4;
                *(f16x4*)dst = hv;
            }

            // (3) MFMA + epilogue for chunk ch (full-K, no exchange)
            if (ch <= 7) {
                const char* q1b = (const char*)&Q1[par][0] + c * (QS * 2);
                const char* q2b = (const char*)&Q2[par][0] + c * (QS * 2);
                if (notLast) {   // ---- L1: [h1 | x] @ [U1;W1], 2 acc chains ----
                    f32x4 a0{0.f, 0.f, 0.f, 0.f}, a1 = a0;
#pragma unroll
                    for (int kc = 0; kc < 8; ++kc) {
                        f16x8 av = *(const f16x8*)(q1b + kc * 64 + kq * 16);
                        MFMA16(av, w1f[kc], a0);
                    }
#pragma unroll
                    for (int kc = 8; kc < 16; ++kc) {
                        f16x8 av = *(const f16x8*)(q1b + kc * 64 + kq * 16);
                        MFMA16(av, w1f[kc], a1);
                    }
                    {
                        f16x8 av = *(const f16x8*)&Xp[par][c][kq * 8];
                        MFMA16(av, w1f[16], a0);
                        av = *(const f16x8*)&Xp[par][c][32 + kq * 8];
                        MFMA16(av, w1f[17], a1);
                    }
                    lstm_epi(a0 + a1, bias1, c1s, &hst[par][0][0][0], ch * 16, kq, c, ub0);
                }
                if (s >= 1) {    // ---- L2: [h2 | h1] @ [U2;W2], 2 acc chains ----
                    f32x4 b0{0.f, 0.f, 0.f, 0.f}, b1 = b0;
#pragma unroll
                    for (int kc = 0; kc < 16; ++kc) {
                        f16x8 av = *(const f16x8*)(q2b + kc * 64 + kq * 16);
                        MFMA16(av, w2f[kc], b0);
                    }
#pragma unroll
                    for (int kc = 0; kc < 16; ++kc) {
                        f16x8 av = *(const f16x8*)(q1b + kc * 64 + kq * 16);
                        MFMA16(av, w2f[16 + kc], b1);
                    }
                    lstm_epi(b0 + b1, bias2, c2s, &hst[par][1][0][0], ch * 16, kq, c, ub0);
                }
            }

            // (4) x(ch+1) -> Xp[par^1]
            if (havex)
                *(f16x2*)&Xp[par ^ 1][xrow][xc2] =
                    (f16x2){(_Float16)xnext.x, (_Float16)xnext.y};

            __syncthreads();   // single barrier per region
        }

        // ---- rowgroup barrier, relaxed (validated r9) ----
        if (tid == 0) {
            __hip_atomic_fetch_add(&bar[rg * 32], 1u,
                                   __ATOMIC_RELAXED, __HIP_MEMORY_SCOPE_AGENT);
            const unsigned target = 16u * (unsigned)(s + 1);
            while (__hip_atomic_load(&bar[rg * 32],
                                     __ATOMIC_RELAXED, __HIP_MEMORY_SCOPE_AGENT) < target)
                __builtin_amdgcn_s_sleep(2);
        }
        __syncthreads();
    }

    // ---- dense head: out = h2_127 @ Wd + bd (cg==0 blocks; 4 threads/row) ----
    if (cg == 0) {
        const _Float16* hf = h2b + (size_t)((TT + 1) & 1) * 2048 * HH;
        int row = tid >> 2, part = tid & 3;
        const _Float16* hr = hf + (size_t)(r0 + row) * HH + part * 128;
        const float* wd = Wd + part * 128;
        float ssum = 0.f;
#pragma unroll
        for (int u8 = 0; u8 < 16; ++u8) {
            f16x8 hv = *(const f16x8*)(hr + u8 * 8);
#pragma unroll
            for (int k = 0; k < 8; ++k) ssum += (float)hv[k] * wd[u8 * 8 + k];
        }
        ssum += __shfl_xor(ssum, 1);
        ssum += __shfl_xor(ssum, 2);
        if (part == 0) out[r0 + row] = ssum + bd[0];
    }
}

extern "C" void kernel_launch(void* const* d_in, const int* in_sizes, int n_in,
                              void* d_out, int out_size, void* d_ws, size_t ws_size,
                              hipStream_t stream)
{
    const float* x  = (const float*)d_in[0];
    const float* W1 = (const float*)d_in[1];
    const float* U1 = (const float*)d_in[2];
    const float* b1 = (const float*)d_in[3];
    const float* W2 = (const float*)d_in[4];
    const float* U2 = (const float*)d_in[5];
    const float* b2 = (const float*)d_in[6];
    const float* Wd = (const float*)d_in[7];
    const float* bd = (const float*)d_in[8];
    float* out = (float*)d_out;

    char* ws = (char*)d_ws;
    size_t off = 0;
    _Float16* Bp1 = (_Float16*)(ws + off); off += (size_t)K1 * GG * 2;
    _Float16* Bp2 = (_Float16*)(ws + off); off += (size_t)K2 * GG * 2;
    float*    pb1 = (float*)(ws + off);    off += (size_t)GG * 4;
    float*    pb2 = (float*)(ws + off);    off += (size_t)GG * 4;
    _Float16* h1b = (_Float16*)(ws + off); off += (size_t)2 * 2048 * HH * 2;
    _Float16* h2b = (_Float16*)(ws + off); off += (size_t)2 * 2048 * HH * 2;
    unsigned* bar = (unsigned*)(ws + off); off += 16 * 32 * 4;

    hipMemsetAsync(h1b, 0, (size_t)2 * 2048 * HH * 2, stream);
    hipMemsetAsync(h2b, 0, (size_t)2 * 2048 * HH * 2, stream);
    hipMemsetAsync(bar, 0, 16 * 32 * 4, stream);

    pack_weights<<<KB1, 256, 0, stream>>>(U1, W1, b1, KB1, HH, Bp1, pb1);
    pack_weights<<<KB2, 256, 0, stream>>>(U2, W2, b2, KB2, HH, Bp2, pb2);
    lstm_persist<<<NBLK, 512, 0, stream>>>(x, Bp1, pb1, Bp2, pb2, Wd, bd,
                                           h1b, h2b, bar, out);
}